// Round 3
// baseline (7834.927 us; speedup 1.0000x reference)
//
#include <hip/hip_runtime.h>
#include <cstdint>
#include <cstddef>

// B=1, N=2048, CS=384, H=12, C=16, PQK=4, PV=8
#define Hh    12
#define Nseq  2048
#define CSd   384
#define INFm  100000.0f
#define EPSm  1e-8f

// ws float offsets (separate buffer per projection -- NO concat stage)
#define O_Q      0           // 2048*192   q
#define O_KV     393216      // 2048*384   kv
#define O_QPR    1179648     // 2048*144   q_pts raw (pre-rotation)
#define O_KVPR   1474560     // 2048*432   kv_pts raw
#define O_QPTS   2359296     // 2048*12*12 rotated q_pts  (n,h,p,d)
#define O_KPTS   2654208     // 2048*12*12 rotated k_pts
#define O_VPTS   2949120     // 2048*12*24 rotated v_pts
#define O_Q2     3538944     // 2048*12
#define O_K2     3563520     // 2048*12
#define O_FEATS  3588096     // 2048*576
#define WSF      4767744

// ---------------------------------------------------------------------------
// Naive GEMM: C[m][o] = sum_k A[m][k] * W[o][k] + b[o].  One thread/element.
// Matches einsum('bni,oi->bno', A, W) + b exactly.
// ---------------------------------------------------------------------------
__global__ void ngemm(const float* A, const float* W, const float* b,
                      float* C, int M, int Nc, int K)
{
    int idx = blockIdx.x * 256 + threadIdx.x;
    if (idx >= M * Nc) return;
    int m = idx / Nc, o = idx % Nc;
    const float* a = A + (size_t)m * K;
    const float* w = W + (size_t)o * K;
    float acc = b[o];
    for (int k = 0; k < K; ++k) acc += a[k] * w[k];
    C[idx] = acc;
}

// ---------------------------------------------------------------------------
// Points: one thread per (n,h).
// raw q_pts:  (N,144) reshaped (N,3,48):  off = d*48  + h*4  + p
// raw kv_pts: (N,432) reshaped (N,3,144): off = d*144 + h*12 + pt
// rotated: out_d = sum_j rot[n,d,j]*raw_j + trans[n,d]   ('bnij,bnmj->bnmi')
// k_pts = pts[:4], v_pts = pts[4:12].
// ---------------------------------------------------------------------------
__global__ void npoints(const float* qpr, const float* kvpr,
                        const float* rot, const float* trans,
                        float* qpts, float* kpts, float* vpts,
                        float* q2, float* k2)
{
    int idx = blockIdx.x * 256 + threadIdx.x;   // n*12 + h
    if (idx >= Nseq * Hh) return;
    int n = idx / Hh, h = idx % Hh;

    float R[9], T[3];
    for (int z = 0; z < 9; ++z) R[z] = rot[(size_t)n * 9 + z];
    for (int d = 0; d < 3; ++d) T[d] = trans[(size_t)n * 3 + d];

    const float* qr = qpr  + (size_t)n * 144;
    const float* kr = kvpr + (size_t)n * 432;

    float s2 = 0.0f;
    for (int p = 0; p < 4; ++p) {
        float r0 = qr[0 * 48 + h * 4 + p];
        float r1 = qr[1 * 48 + h * 4 + p];
        float r2 = qr[2 * 48 + h * 4 + p];
        for (int d = 0; d < 3; ++d) {
            float o = R[d * 3 + 0] * r0 + R[d * 3 + 1] * r1 + R[d * 3 + 2] * r2 + T[d];
            qpts[((size_t)n * Hh + h) * 12 + p * 3 + d] = o;
            s2 += o * o;
        }
    }
    q2[idx] = s2;

    float s2k = 0.0f;
    for (int pt = 0; pt < 12; ++pt) {
        float r0 = kr[0 * 144 + h * 12 + pt];
        float r1 = kr[1 * 144 + h * 12 + pt];
        float r2 = kr[2 * 144 + h * 12 + pt];
        for (int d = 0; d < 3; ++d) {
            float o = R[d * 3 + 0] * r0 + R[d * 3 + 1] * r1 + R[d * 3 + 2] * r2 + T[d];
            if (pt < 4) {
                kpts[((size_t)n * Hh + h) * 12 + pt * 3 + d] = o;
                s2k += o * o;
            } else {
                vpts[((size_t)n * Hh + h) * 24 + (pt - 4) * 3 + d] = o;
            }
        }
    }
    k2[idx] = s2k;
}

// ---------------------------------------------------------------------------
// Attention + epilogue: ONE THREAD per (i,h). Full j loop, direct exp
// (logits provably < ~2: pt term <= 0, |qk-term| < ~1; no overflow).
// q layout:  Q[i*192 + h*16 + c]
// kv layout: KV[j*384 + h*32 + c]  (c<16: k, c>=16: v)
// feats row (576): [ o(192) | x(96) | y(96) | z(96) | dist(96) ]
// ---------------------------------------------------------------------------
__global__ void nattn(const float* Q, const float* KV,
                      const float* qpts, const float* kpts, const float* vpts,
                      const float* q2, const float* k2,
                      const float* mask, const float* hwv,
                      const float* rot, const float* trans,
                      float* feats)
{
    int idx = blockIdx.x * 256 + threadIdx.x;   // i*12 + h
    if (idx >= Nseq * Hh) return;
    int i = idx / Hh, h = idx % Hh;

    // hw = softplus(head_weights[h]) * sqrt(1/54);  whw = 0.5*hw
    float whw = 0.5f * logf(1.0f + expf(hwv[h])) * 0.13608276348795434f;
    const float scale_a = 0.14433756729740643f;   // sqrt(1/(3*16))

    float qs[16];
    for (int c = 0; c < 16; ++c) qs[c] = Q[(size_t)i * 192 + h * 16 + c] * scale_a;
    float qp[12];
    for (int z = 0; z < 12; ++z) qp[z] = qpts[((size_t)i * Hh + h) * 12 + z] * (2.0f * whw);

    float mi  = mask[i];
    float b_i = -whw * q2[(size_t)i * Hh + h];

    float l = 0.0f;
    float acc[40];
    for (int z = 0; z < 40; ++z) acc[z] = 0.0f;

    for (int j = 0; j < Nseq; ++j) {
        const float* kvj = KV   + (size_t)j * 384 + h * 32;
        const float* kpj = kpts + ((size_t)j * Hh + h) * 12;
        const float* vpj = vpts + ((size_t)j * Hh + h) * 24;

        float logit = (mi * mask[j] - 1.0f) * INFm + b_i - whw * k2[(size_t)j * Hh + h];
        for (int c = 0; c < 16; ++c) logit += qs[c] * kvj[c];
        for (int z = 0; z < 12; ++z) logit += qp[z] * kpj[z];

        float w = expf(logit);
        l += w;
        for (int c = 0; c < 16; ++c) acc[c]      += w * kvj[16 + c];
        for (int z = 0; z < 24; ++z) acc[16 + z] += w * vpj[z];
    }

    float inv = 1.0f / l;
    for (int z = 0; z < 40; ++z) acc[z] *= inv;

    float* f = feats + (size_t)i * 576;
    for (int c = 0; c < 16; ++c) f[h * 16 + c] = acc[c];

    float R[9], T[3];
    for (int z = 0; z < 9; ++z) R[z] = rot[(size_t)i * 9 + z];
    for (int d = 0; d < 3; ++d) T[d] = trans[(size_t)i * 3 + d];

    for (int p = 0; p < 8; ++p) {
        float g0 = acc[16 + p * 3 + 0] - T[0];
        float g1 = acc[16 + p * 3 + 1] - T[1];
        float g2 = acc[16 + p * 3 + 2] - T[2];
        // 'bnji,bnhpj->bnhpi': out_i = sum_j rot[j][i] * g_j  (rot^T)
        float xx = R[0] * g0 + R[3] * g1 + R[6] * g2;
        float yy = R[1] * g0 + R[4] * g1 + R[7] * g2;
        float zz = R[2] * g0 + R[5] * g1 + R[8] * g2;
        float dist = sqrtf(xx * xx + yy * yy + zz * zz + EPSm);
        f[192 + h * 8 + p] = xx;
        f[288 + h * 8 + p] = yy;
        f[384 + h * 8 + p] = zz;
        f[480 + h * 8 + p] = dist;
    }
}

// ---------------------------------------------------------------------------
extern "C" void kernel_launch(void* const* d_in, const int* in_sizes, int n_in,
                              void* d_out, int out_size, void* d_ws, size_t ws_size,
                              hipStream_t stream)
{
    const float* s     = (const float*)d_in[0];
    const float* rot   = (const float*)d_in[1];
    const float* trans = (const float*)d_in[2];
    const float* mask  = (const float*)d_in[3];
    const float* Wq    = (const float*)d_in[4];
    const float* bq    = (const float*)d_in[5];
    const float* Wkv   = (const float*)d_in[6];
    const float* bkv   = (const float*)d_in[7];
    const float* Wqp   = (const float*)d_in[8];
    const float* bqp   = (const float*)d_in[9];
    const float* Wkvp  = (const float*)d_in[10];
    const float* bkvp  = (const float*)d_in[11];
    const float* hwv   = (const float*)d_in[12];
    const float* Wout  = (const float*)d_in[13];
    const float* bout  = (const float*)d_in[14];
    float* out = (float*)d_out;
    float* ws  = (float*)d_ws;

    if (ws_size < (size_t)WSF * sizeof(float)) return;

    float* Q     = ws + O_Q;
    float* KV    = ws + O_KV;
    float* QPR   = ws + O_QPR;
    float* KVPR  = ws + O_KVPR;
    float* qpts  = ws + O_QPTS;
    float* kpts  = ws + O_KPTS;
    float* vpts  = ws + O_VPTS;
    float* q2    = ws + O_Q2;
    float* k2    = ws + O_K2;
    float* feats = ws + O_FEATS;

    // 1) four independent naive projections (no concat stage at all)
    ngemm<<<dim3((2048 * 192 + 255) / 256), 256, 0, stream>>>(s, Wq,   bq,   Q,    2048, 192, 384);
    ngemm<<<dim3((2048 * 384 + 255) / 256), 256, 0, stream>>>(s, Wkv,  bkv,  KV,   2048, 384, 384);
    ngemm<<<dim3((2048 * 144 + 255) / 256), 256, 0, stream>>>(s, Wqp,  bqp,  QPR,  2048, 144, 384);
    ngemm<<<dim3((2048 * 432 + 255) / 256), 256, 0, stream>>>(s, Wkvp, bkvp, KVPR, 2048, 432, 384);

    // 2) rotate/translate points, q2/k2
    npoints<<<dim3(96), 256, 0, stream>>>(QPR, KVPR, rot, trans, qpts, kpts, vpts, q2, k2);

    // 3) attention + epilogue, one thread per (i,h)
    nattn<<<dim3(96), 256, 0, stream>>>(Q, KV, qpts, kpts, vpts, q2, k2,
                                        mask, hwv, rot, trans, feats);

    // 4) out = feats @ Wout^T + bout
    ngemm<<<dim3((2048 * 384 + 255) / 256), 256, 0, stream>>>(feats, Wout, bout, out, 2048, 384, 576);
}

// Round 4
// 381.054 us; speedup vs baseline: 20.5612x; 20.5612x over previous
//
#include <hip/hip_runtime.h>
#include <hip/hip_bf16.h>
#include <cstdint>
#include <cstddef>

// Problem constants
#define Hh    12
#define Nseq  2048
#define PSTR  1152      // concat projection width: 192 q | 384 kv | 144 qp | 432 kvp
#define INFm  100000.0f
#define EPSm  1e-8f

// ws offsets (in floats), all 16B aligned. Total 20.8 MB (ws >= 29 MB proven in r1).
#define OFF_WALL  0               // 1152*384
#define OFF_BALL  442368          // 1152
#define OFF_PALL  443520          // 2048*1152
#define OFF_QPTS  2802816         // 2048*12*12
#define OFF_KPTS  3097728         // 2048*12*12
#define OFF_VPTS  3392640         // 2048*12*24
#define OFF_Q2    3982464         // 2048*12
#define OFF_K2    4007040         // 2048*12
#define OFF_FEATS 4031616         // 2048*576
#define WS_FLOATS 5211264

// ---------------------------------------------------------------------------
// Concat weights/biases. Wall row r: [0,192)=Wq, [192,576)=Wkv,
// [576,720)=Wqp, [720,1152)=Wkvp.  (Exonerated: fed r1/r2 correctly.)
// ---------------------------------------------------------------------------
__global__ __launch_bounds__(256) void concat_w(
    const float* __restrict__ Wq, const float* __restrict__ Wkv,
    const float* __restrict__ Wqp, const float* __restrict__ Wkvp,
    const float* __restrict__ bq, const float* __restrict__ bkv,
    const float* __restrict__ bqp, const float* __restrict__ bkvp,
    float* __restrict__ Wall, float* __restrict__ ball)
{
    int idx = blockIdx.x * 256 + threadIdx.x;
    if (idx < 1152 * 384) {
        int r = idx / 384, c = idx % 384;
        float v;
        if (r < 192)      v = Wq [(size_t)r * 384 + c];
        else if (r < 576) v = Wkv[(size_t)(r - 192) * 384 + c];
        else if (r < 720) v = Wqp[(size_t)(r - 576) * 384 + c];
        else              v = Wkvp[(size_t)(r - 720) * 384 + c];
        Wall[idx] = v;
    }
    if (idx < 1152) {
        float v;
        if (idx < 192)      v = bq[idx];
        else if (idx < 576) v = bkv[idx - 192];
        else if (idx < 720) v = bqp[idx - 576];
        else                v = bkvp[idx - 720];
        ball[idx] = v;
    }
}

// ---------------------------------------------------------------------------
// C[m][n] = sum_k A[m][k] * W[n][k] + bias[n].  BM=BN=64, BK=16, 256 thr,
// 4x4/thread. All dims divide evenly (M=2048; Nn=1152/384; K=384/576).
// ---------------------------------------------------------------------------
__global__ __launch_bounds__(256) void gemm_bt(
    const float* __restrict__ A, const float* __restrict__ W,
    const float* __restrict__ bias, float* __restrict__ Cm,
    int M, int Nn, int K)
{
    __shared__ float As[16][68];
    __shared__ float Bs[16][68];
    const int bm = blockIdx.y * 64;
    const int bn = blockIdx.x * 64;
    const int t  = threadIdx.x;
    const int tx = t & 15;
    const int ty = t >> 4;

    float acc[4][4] = {};

    for (int k0 = 0; k0 < K; k0 += 16) {
        #pragma unroll
        for (int u = 0; u < 4; ++u) {
            int idx = t + u * 256;
            int m = idx >> 4, k = idx & 15;
            As[k][m] = A[(size_t)(bm + m) * K + k0 + k];
            Bs[k][m] = W[(size_t)(bn + m) * K + k0 + k];
        }
        __syncthreads();
        #pragma unroll
        for (int k = 0; k < 16; ++k) {
            float4 av = *(const float4*)&As[k][ty * 4];
            float4 bv = *(const float4*)&Bs[k][tx * 4];
            float a[4] = {av.x, av.y, av.z, av.w};
            float b[4] = {bv.x, bv.y, bv.z, bv.w};
            #pragma unroll
            for (int i2 = 0; i2 < 4; ++i2)
                #pragma unroll
                for (int j2 = 0; j2 < 4; ++j2)
                    acc[i2][j2] = fmaf(a[i2], b[j2], acc[i2][j2]);
        }
        __syncthreads();
    }

    const float* bp = bias + bn + tx * 4;
    float4 bb = *(const float4*)bp;
    #pragma unroll
    for (int i2 = 0; i2 < 4; ++i2) {
        float4 o;
        o.x = acc[i2][0] + bb.x;
        o.y = acc[i2][1] + bb.y;
        o.z = acc[i2][2] + bb.z;
        o.w = acc[i2][3] + bb.w;
        *(float4*)&Cm[(size_t)(bm + ty * 4 + i2) * Nn + bn + tx * 4] = o;
    }
}

// ---------------------------------------------------------------------------
// Rotate/translate point projections (exonerated; identical to verified
// npoints except reading from the concat layout).
// P row: [0,192) q | [192,576) kv | [576,720) qp raw | [720,1152) kvp raw
// qp raw ch = d*48 + h*4 + p ; kvp raw ch = d*144 + h*12 + pt
// ---------------------------------------------------------------------------
__global__ __launch_bounds__(256) void rotate_pts(
    const float* __restrict__ P, const float* __restrict__ rot,
    const float* __restrict__ trans,
    float* __restrict__ qpts, float* __restrict__ kpts, float* __restrict__ vpts,
    float* __restrict__ q2, float* __restrict__ k2)
{
    int idx = blockIdx.x * 256 + threadIdx.x;    // n*H + h
    if (idx >= Nseq * Hh) return;
    int n = idx / Hh, h = idx % Hh;

    float R[9], T[3];
    #pragma unroll
    for (int z = 0; z < 9; ++z) R[z] = rot[(size_t)n * 9 + z];
    #pragma unroll
    for (int d = 0; d < 3; ++d) T[d] = trans[(size_t)n * 3 + d];

    const float* base = P + (size_t)n * PSTR;

    float s2 = 0.f;
    #pragma unroll
    for (int p = 0; p < 4; ++p) {
        float r0 = base[576 +   0 + h * 4 + p];
        float r1 = base[576 +  48 + h * 4 + p];
        float r2 = base[576 +  96 + h * 4 + p];
        #pragma unroll
        for (int d = 0; d < 3; ++d) {
            float o = R[d*3+0]*r0 + R[d*3+1]*r1 + R[d*3+2]*r2 + T[d];
            qpts[((size_t)n * Hh + h) * 12 + p * 3 + d] = o;
            s2 += o * o;
        }
    }
    q2[idx] = s2;

    float s2k = 0.f;
    #pragma unroll
    for (int pt = 0; pt < 12; ++pt) {
        float r0 = base[720 +   0 + h * 12 + pt];
        float r1 = base[720 + 144 + h * 12 + pt];
        float r2 = base[720 + 288 + h * 12 + pt];
        #pragma unroll
        for (int d = 0; d < 3; ++d) {
            float o = R[d*3+0]*r0 + R[d*3+1]*r1 + R[d*3+2]*r2 + T[d];
            if (pt < 4) {
                kpts[((size_t)n * Hh + h) * 12 + pt * 3 + d] = o;
                s2k += o * o;
            } else {
                vpts[((size_t)n * Hh + h) * 24 + (pt - 4) * 3 + d] = o;
            }
        }
    }
    k2[idx] = s2k;
}

// ---------------------------------------------------------------------------
// Fused attention + epilogue.  *** r1/r2 BUG FIXED: per-j strides are
// kpts += 144 (H*12) and vpts += 288 (H*24), NOT 12/24. ***
// Direct exp (no online max): logits bounded ~[-30,+5], no overflow.
// Grid 384 = 12 h x 32 i-blocks of 64. 4 waves split j (512 each), LDS
// sum-merge, threads 0..63 run the epilogue (verbatim from verified r3).
// ---------------------------------------------------------------------------
__global__ __launch_bounds__(256) void attn_fused(
    const float* __restrict__ P, const float* __restrict__ qpts,
    const float* __restrict__ kpts, const float* __restrict__ vpts,
    const float* __restrict__ q2, const float* __restrict__ k2,
    const float* __restrict__ mask, const float* __restrict__ hwv,
    const float* __restrict__ rot, const float* __restrict__ trans,
    float* __restrict__ feats)
{
    __shared__ float sL[4][64];          // 1 KB
    __shared__ float sA[4][64][40];      // 40 KB

    const int b    = blockIdx.x;
    const int h    = b >> 5;
    const int iblk = b & 31;
    const int t    = threadIdx.x;
    const int lane = t & 63;
    const int w    = t >> 6;
    const int i    = iblk * 64 + lane;

    const float whw = 0.5f * logf(1.0f + expf(hwv[h])) * 0.13608276348795434f; // sqrt(1/54)
    const float scale_a = 0.14433756729740643f;   // sqrt(1/48)

    float qs[16], qp[12];
    {
        const float* qrow = P + (size_t)i * PSTR + h * 16;
        #pragma unroll
        for (int c = 0; c < 16; ++c) qs[c] = qrow[c] * scale_a;
        const float* qpr = qpts + ((size_t)i * Hh + h) * 12;
        float tw = 2.0f * whw;
        #pragma unroll
        for (int z = 0; z < 12; ++z) qp[z] = qpr[z] * tw;
    }
    const float mi  = mask[i];
    const float b_i = -whw * q2[(size_t)i * Hh + h];

    float l = 0.f;
    float acc[40];
    #pragma unroll
    for (int z = 0; z < 40; ++z) acc[z] = 0.f;

    // wave-uniform j base -> scalar (broadcast) loads for all k-side data
    const int jbeg = __builtin_amdgcn_readfirstlane(w * 512);

    const float* pkv = P    + (size_t)jbeg * PSTR + 192 + h * 32; // k[16] v[16]
    const float* pkp = kpts + (size_t)jbeg * 144 + h * 12;        // stride 144/j
    const float* pvp = vpts + (size_t)jbeg * 288 + h * 24;        // stride 288/j
    const float* pk2 = k2   + (size_t)jbeg * Hh  + h;             // stride 12/j
    const float* pms = mask + jbeg;

    for (int jj = 0; jj < 512; ++jj) {
        float logit = fmaf(mi, pms[jj], -1.0f) * INFm + b_i - whw * pk2[0];
        #pragma unroll
        for (int c = 0; c < 16; ++c) logit = fmaf(qs[c], pkv[c], logit);
        #pragma unroll
        for (int z = 0; z < 12; ++z) logit = fmaf(qp[z], pkp[z], logit);

        float wj = __expf(logit);
        l += wj;
        #pragma unroll
        for (int c = 0; c < 16; ++c) acc[c]      = fmaf(wj, pkv[16 + c], acc[c]);
        #pragma unroll
        for (int z = 0; z < 24; ++z) acc[16 + z] = fmaf(wj, pvp[z],      acc[16 + z]);

        pkv += PSTR; pkp += 144; pvp += 288; pk2 += Hh;   // FIXED strides
    }

    sL[w][lane] = l;
    #pragma unroll
    for (int z = 0; z < 40; ++z) sA[w][lane][z] = acc[z];
    __syncthreads();

    if (t < 64) {
        float L = 0.f;
        float o[40];
        #pragma unroll
        for (int z = 0; z < 40; ++z) o[z] = 0.f;
        #pragma unroll
        for (int s = 0; s < 4; ++s) {
            L += sL[s][t];
            #pragma unroll
            for (int z = 0; z < 40; ++z) o[z] += sA[s][t][z];
        }
        float inv = 1.0f / L;
        #pragma unroll
        for (int z = 0; z < 40; ++z) o[z] *= inv;

        float* f = feats + (size_t)i * 576;
        #pragma unroll
        for (int c = 0; c < 16; ++c) f[h * 16 + c] = o[c];

        float R[9], T[3];
        #pragma unroll
        for (int z = 0; z < 9; ++z) R[z] = rot[(size_t)i * 9 + z];
        #pragma unroll
        for (int d = 0; d < 3; ++d) T[d] = trans[(size_t)i * 3 + d];

        #pragma unroll
        for (int p = 0; p < 8; ++p) {
            float g0 = o[16 + p * 3 + 0] - T[0];
            float g1 = o[16 + p * 3 + 1] - T[1];
            float g2 = o[16 + p * 3 + 2] - T[2];
            float xx = R[0] * g0 + R[3] * g1 + R[6] * g2;
            float yy = R[1] * g0 + R[4] * g1 + R[7] * g2;
            float zz = R[2] * g0 + R[5] * g1 + R[8] * g2;
            float dist = sqrtf(xx * xx + yy * yy + zz * zz + EPSm);
            f[192 + h * 8 + p] = xx;
            f[288 + h * 8 + p] = yy;
            f[384 + h * 8 + p] = zz;
            f[480 + h * 8 + p] = dist;
        }
    }
}

// ---------------------------------------------------------------------------
extern "C" void kernel_launch(void* const* d_in, const int* in_sizes, int n_in,
                              void* d_out, int out_size, void* d_ws, size_t ws_size,
                              hipStream_t stream)
{
    const float* s     = (const float*)d_in[0];
    const float* rot   = (const float*)d_in[1];
    const float* trans = (const float*)d_in[2];
    const float* mask  = (const float*)d_in[3];
    const float* Wq    = (const float*)d_in[4];
    const float* bq    = (const float*)d_in[5];
    const float* Wkv   = (const float*)d_in[6];
    const float* bkv   = (const float*)d_in[7];
    const float* Wqp   = (const float*)d_in[8];
    const float* bqp   = (const float*)d_in[9];
    const float* Wkvp  = (const float*)d_in[10];
    const float* bkvp  = (const float*)d_in[11];
    const float* hwv   = (const float*)d_in[12];
    const float* Wout  = (const float*)d_in[13];
    const float* bout  = (const float*)d_in[14];
    float* out = (float*)d_out;
    float* ws  = (float*)d_ws;

    if (ws_size < (size_t)WS_FLOATS * sizeof(float)) return;

    float* Wall  = ws + OFF_WALL;
    float* ball  = ws + OFF_BALL;
    float* Pall  = ws + OFF_PALL;
    float* qpts  = ws + OFF_QPTS;
    float* kpts  = ws + OFF_KPTS;
    float* vpts  = ws + OFF_VPTS;
    float* q2    = ws + OFF_Q2;
    float* k2    = ws + OFF_K2;
    float* feats = ws + OFF_FEATS;

    concat_w<<<dim3(1728), 256, 0, stream>>>(Wq, Wkv, Wqp, Wkvp,
                                             bq, bkv, bqp, bkvp, Wall, ball);

    gemm_bt<<<dim3(1152 / 64, 2048 / 64), 256, 0, stream>>>(
        s, Wall, ball, Pall, 2048, 1152, 384);

    rotate_pts<<<dim3(96), 256, 0, stream>>>(Pall, rot, trans, qpts, kpts, vpts, q2, k2);

    attn_fused<<<dim3(384), 256, 0, stream>>>(
        Pall, qpts, kpts, vpts, q2, k2, mask, hwv, rot, trans, feats);

    gemm_bt<<<dim3(384 / 64, 2048 / 64), 256, 0, stream>>>(
        feats, Wout, bout, out, 2048, 384, 576);
}

// Round 5
// 285.090 us; speedup vs baseline: 27.4823x; 1.3366x over previous
//
#include <hip/hip_runtime.h>
#include <hip/hip_bf16.h>
#include <cstdint>
#include <cstddef>

// Problem constants
#define Hh    12
#define Nseq  2048
#define PSTR  1152      // concat projection width: 192 q | 384 kv | 144 qp | 432 kvp
#define INFm  100000.0f
#define EPSm  1e-8f

// ws offsets (floats). Total 7,226,496 fl = 28.9 MB <= proven 29.1 MB budget.
#define OFF_WALL  0               // 1152*384      (dead after gemm1)
#define OFF_BALL  442368          // 1152
#define OFF_PALL  443520          // 2048*1152     (q live through attn)
#define OFF_QPTS  2802816         // 2048*12*12    (q-side, [n][h][12])
#define OFF_Q2    3097728         // 2048*12       ([n*12+h])
#define OFF_KPT   3122304         // 12*2048*12    ([h][j][12] transposed)
#define OFF_VPT   3417216         // 12*2048*24    ([h][j][24] transposed)
#define OFF_K2T   4007040         // 12*2048       ([h][j])
#define OFF_FEATS 4031616         // 2048*576
#define OFF_P0    5211264         // 12*2048*41    (j-half 0 partials)
#define OFF_P1    6218880         // 12*2048*41    (j-half 1 partials)
#define WS_FLOATS 7226496

// ---------------------------------------------------------------------------
// Concat weights/biases (exonerated r1-r4).
// ---------------------------------------------------------------------------
__global__ __launch_bounds__(256) void concat_w(
    const float* __restrict__ Wq, const float* __restrict__ Wkv,
    const float* __restrict__ Wqp, const float* __restrict__ Wkvp,
    const float* __restrict__ bq, const float* __restrict__ bkv,
    const float* __restrict__ bqp, const float* __restrict__ bkvp,
    float* __restrict__ Wall, float* __restrict__ ball)
{
    int idx = blockIdx.x * 256 + threadIdx.x;
    if (idx < 1152 * 384) {
        int r = idx / 384, c = idx % 384;
        float v;
        if (r < 192)      v = Wq [(size_t)r * 384 + c];
        else if (r < 576) v = Wkv[(size_t)(r - 192) * 384 + c];
        else if (r < 720) v = Wqp[(size_t)(r - 576) * 384 + c];
        else              v = Wkvp[(size_t)(r - 720) * 384 + c];
        Wall[idx] = v;
    }
    if (idx < 1152) {
        float v;
        if (idx < 192)      v = bq[idx];
        else if (idx < 576) v = bkv[idx - 192];
        else if (idx < 720) v = bqp[idx - 576];
        else                v = bkvp[idx - 720];
        ball[idx] = v;
    }
}

// ---------------------------------------------------------------------------
// C[m][n] = sum_k A[m][k]*W[n][k] + bias[n]. 64x64 tile, verified r4.
// ---------------------------------------------------------------------------
__global__ __launch_bounds__(256) void gemm_bt(
    const float* __restrict__ A, const float* __restrict__ W,
    const float* __restrict__ bias, float* __restrict__ Cm,
    int M, int Nn, int K)
{
    __shared__ float As[16][68];
    __shared__ float Bs[16][68];
    const int bm = blockIdx.y * 64;
    const int bn = blockIdx.x * 64;
    const int t  = threadIdx.x;
    const int tx = t & 15;
    const int ty = t >> 4;

    float acc[4][4] = {};

    for (int k0 = 0; k0 < K; k0 += 16) {
        #pragma unroll
        for (int u = 0; u < 4; ++u) {
            int idx = t + u * 256;
            int m = idx >> 4, k = idx & 15;
            As[k][m] = A[(size_t)(bm + m) * K + k0 + k];
            Bs[k][m] = W[(size_t)(bn + m) * K + k0 + k];
        }
        __syncthreads();
        #pragma unroll
        for (int k = 0; k < 16; ++k) {
            float4 av = *(const float4*)&As[k][ty * 4];
            float4 bv = *(const float4*)&Bs[k][tx * 4];
            float a[4] = {av.x, av.y, av.z, av.w};
            float b[4] = {bv.x, bv.y, bv.z, bv.w};
            #pragma unroll
            for (int i2 = 0; i2 < 4; ++i2)
                #pragma unroll
                for (int j2 = 0; j2 < 4; ++j2)
                    acc[i2][j2] = fmaf(a[i2], b[j2], acc[i2][j2]);
        }
        __syncthreads();
    }

    const float* bp = bias + bn + tx * 4;
    float4 bb = *(const float4*)bp;
    #pragma unroll
    for (int i2 = 0; i2 < 4; ++i2) {
        float4 o;
        o.x = acc[i2][0] + bb.x;
        o.y = acc[i2][1] + bb.y;
        o.z = acc[i2][2] + bb.z;
        o.w = acc[i2][3] + bb.w;
        *(float4*)&Cm[(size_t)(bm + ty * 4 + i2) * Nn + bn + tx * 4] = o;
    }
}

// ---------------------------------------------------------------------------
// Rotate/translate points; q-side in [n][h] layout, k-side TRANSPOSED to
// per-head streams [h][j][...] so attention's per-j loads are contiguous.
// Math verbatim from verified rotate_pts.
// ---------------------------------------------------------------------------
__global__ __launch_bounds__(256) void rotate_pack(
    const float* __restrict__ P, const float* __restrict__ rot,
    const float* __restrict__ trans,
    float* __restrict__ qpts, float* __restrict__ q2,
    float* __restrict__ KPT, float* __restrict__ VPT, float* __restrict__ K2T)
{
    int idx = blockIdx.x * 256 + threadIdx.x;    // n*H + h
    if (idx >= Nseq * Hh) return;
    int n = idx / Hh, h = idx % Hh;

    float R[9], T[3];
    #pragma unroll
    for (int z = 0; z < 9; ++z) R[z] = rot[(size_t)n * 9 + z];
    #pragma unroll
    for (int d = 0; d < 3; ++d) T[d] = trans[(size_t)n * 3 + d];

    const float* base = P + (size_t)n * PSTR;

    float s2 = 0.f;
    #pragma unroll
    for (int p = 0; p < 4; ++p) {
        float r0 = base[576 +   0 + h * 4 + p];
        float r1 = base[576 +  48 + h * 4 + p];
        float r2 = base[576 +  96 + h * 4 + p];
        #pragma unroll
        for (int d = 0; d < 3; ++d) {
            float o = R[d*3+0]*r0 + R[d*3+1]*r1 + R[d*3+2]*r2 + T[d];
            qpts[((size_t)n * Hh + h) * 12 + p * 3 + d] = o;
            s2 += o * o;
        }
    }
    q2[idx] = s2;

    float s2k = 0.f;
    #pragma unroll
    for (int pt = 0; pt < 12; ++pt) {
        float r0 = base[720 +   0 + h * 12 + pt];
        float r1 = base[720 + 144 + h * 12 + pt];
        float r2 = base[720 + 288 + h * 12 + pt];
        #pragma unroll
        for (int d = 0; d < 3; ++d) {
            float o = R[d*3+0]*r0 + R[d*3+1]*r1 + R[d*3+2]*r2 + T[d];
            if (pt < 4) {
                KPT[((size_t)h * Nseq + n) * 12 + pt * 3 + d] = o;
                s2k += o * o;
            } else {
                VPT[((size_t)h * Nseq + n) * 24 + (pt - 4) * 3 + d] = o;
            }
        }
    }
    K2T[(size_t)h * Nseq + n] = s2k;
}

// ---------------------------------------------------------------------------
// Logit for one j: 4 parallel partial chains (depth 7) + base.
// ---------------------------------------------------------------------------
__device__ __forceinline__ float logit_one(
    const float* __restrict__ kv, const float* __restrict__ kp,
    float k2v, float mj, const float* qs, const float* qp,
    float mi, float b_i, float whw)
{
    float p0 = qs[0] * kv[0];
    p0 = fmaf(qs[1], kv[1], p0); p0 = fmaf(qs[2], kv[2], p0); p0 = fmaf(qs[3], kv[3], p0);
    p0 = fmaf(qp[0], kp[0], p0); p0 = fmaf(qp[1], kp[1], p0); p0 = fmaf(qp[2], kp[2], p0);
    float p1 = qs[4] * kv[4];
    p1 = fmaf(qs[5], kv[5], p1); p1 = fmaf(qs[6], kv[6], p1); p1 = fmaf(qs[7], kv[7], p1);
    p1 = fmaf(qp[3], kp[3], p1); p1 = fmaf(qp[4], kp[4], p1); p1 = fmaf(qp[5], kp[5], p1);
    float p2 = qs[8] * kv[8];
    p2 = fmaf(qs[9], kv[9], p2); p2 = fmaf(qs[10], kv[10], p2); p2 = fmaf(qs[11], kv[11], p2);
    p2 = fmaf(qp[6], kp[6], p2); p2 = fmaf(qp[7], kp[7], p2); p2 = fmaf(qp[8], kp[8], p2);
    float p3 = qs[12] * kv[12];
    p3 = fmaf(qs[13], kv[13], p3); p3 = fmaf(qs[14], kv[14], p3); p3 = fmaf(qs[15], kv[15], p3);
    p3 = fmaf(qp[9], kp[9], p3); p3 = fmaf(qp[10], kp[10], p3); p3 = fmaf(qp[11], kp[11], p3);
    float base = fmaf(mi, mj, -1.0f) * INFm + fmaf(-whw, k2v, b_i);
    return ((p0 + p1) + (p2 + p3)) + base;
}

// ---------------------------------------------------------------------------
// Attention partials. Grid 768 = h(12) x iblk(32) x jhalf(2); exactly
// 3 blocks/CU (LDS 41984 B). 4 waves split the j-half (256 j each); lane = i
// within 64-row i-block. k-side loads wave-uniform -> SGPR streams. j-unroll
// x2 with independent logit chains. Partials are plain sums (direct exp; no
// overflow: logits < ~5) -> write (L, acc[40]) to part0/part1.
// ---------------------------------------------------------------------------
__global__ __launch_bounds__(256, 3) void attn_part(
    const float* __restrict__ P, const float* __restrict__ qpts,
    const float* __restrict__ q2,
    const float* __restrict__ KPT, const float* __restrict__ VPT,
    const float* __restrict__ K2T,
    const float* __restrict__ mask, const float* __restrict__ hwv,
    float* __restrict__ part0, float* __restrict__ part1)
{
    __shared__ float red[4][64][41];   // 41984 B

    const int b     = blockIdx.x;
    const int h     = b >> 6;          // 0..11
    const int r     = b & 63;
    const int iblk  = r >> 1;          // 0..31
    const int jhalf = r & 1;
    const int t     = threadIdx.x;
    const int lane  = t & 63;
    const int w     = t >> 6;
    const int i     = iblk * 64 + lane;

    const float whw = 0.5f * logf(1.0f + expf(hwv[h])) * 0.13608276348795434f; // *sqrt(1/54)
    const float scale_a = 0.14433756729740643f;   // sqrt(1/48)

    float qs[16], qp[12];
    {
        const float* qrow = P + (size_t)i * PSTR + h * 16;
        #pragma unroll
        for (int c = 0; c < 16; ++c) qs[c] = qrow[c] * scale_a;
        const float* qpr = qpts + ((size_t)i * Hh + h) * 12;
        float tw = 2.0f * whw;
        #pragma unroll
        for (int z = 0; z < 12; ++z) qp[z] = qpr[z] * tw;
    }
    const float mi  = mask[i];
    const float b_i = -whw * q2[(size_t)i * Hh + h];

    float l = 0.f;
    float acc[40];
    #pragma unroll
    for (int z = 0; z < 40; ++z) acc[z] = 0.f;

    // wave-uniform j base -> scalar (SGPR) loads for all k-side streams
    const int jbeg = __builtin_amdgcn_readfirstlane((jhalf * 4 + w) * 256);

    const float* pkv = P   + (size_t)jbeg * PSTR + 192 + h * 32;   // k16|v16, +1152/j
    const float* pkp = KPT + ((size_t)h * Nseq + jbeg) * 12;       // +12/j
    const float* pvp = VPT + ((size_t)h * Nseq + jbeg) * 24;       // +24/j
    const float* pk2 = K2T + (size_t)h * Nseq + jbeg;              // +1/j
    const float* pm  = mask + jbeg;                                // +1/j

    for (int jj = 0; jj < 256; jj += 2) {
        float lgA = logit_one(pkv,        pkp,      pk2[0], pm[0], qs, qp, mi, b_i, whw);
        float lgB = logit_one(pkv + PSTR, pkp + 12, pk2[1], pm[1], qs, qp, mi, b_i, whw);
        float wA = __expf(lgA);
        float wB = __expf(lgB);
        l += wA + wB;
        #pragma unroll
        for (int c = 0; c < 16; ++c)
            acc[c] = fmaf(wA, pkv[16 + c], fmaf(wB, pkv[PSTR + 16 + c], acc[c]));
        #pragma unroll
        for (int z = 0; z < 24; ++z)
            acc[16 + z] = fmaf(wA, pvp[z], fmaf(wB, pvp[24 + z], acc[16 + z]));
        pkv += 2 * PSTR; pkp += 24; pvp += 48; pk2 += 2; pm += 2;
    }

    red[w][lane][0] = l;
    #pragma unroll
    for (int z = 0; z < 40; ++z) red[w][lane][1 + z] = acc[z];
    __syncthreads();

    if (t < 64) {
        float L = 0.f;
        float o[40];
        #pragma unroll
        for (int z = 0; z < 40; ++z) o[z] = 0.f;
        #pragma unroll
        for (int s = 0; s < 4; ++s) {
            L += red[s][t][0];
            #pragma unroll
            for (int z = 0; z < 40; ++z) o[z] += red[s][t][1 + z];
        }
        float* dst = (jhalf ? part1 : part0) + ((size_t)h * Nseq + i) * 41;
        dst[0] = L;
        #pragma unroll
        for (int z = 0; z < 40; ++z) dst[1 + z] = o[z];
    }
}

// ---------------------------------------------------------------------------
// Merge j-halves (plain sums), normalize, epilogue (verbatim from verified
// r3 nattn tail) -> feats (N,576): [ o(192) | x(96) | y(96) | z(96) | d(96) ]
// ---------------------------------------------------------------------------
__global__ __launch_bounds__(256) void attn_fin(
    const float* __restrict__ part0, const float* __restrict__ part1,
    const float* __restrict__ rot, const float* __restrict__ trans,
    float* __restrict__ feats)
{
    int idx = blockIdx.x * 256 + threadIdx.x;   // i*12 + h
    if (idx >= Nseq * Hh) return;
    int i = idx / Hh, h = idx % Hh;

    const float* a = part0 + ((size_t)h * Nseq + i) * 41;
    const float* b = part1 + ((size_t)h * Nseq + i) * 41;

    float L = a[0] + b[0];
    float inv = 1.0f / L;
    float o[40];
    #pragma unroll
    for (int z = 0; z < 40; ++z) o[z] = (a[1 + z] + b[1 + z]) * inv;

    float* f = feats + (size_t)i * 576;
    #pragma unroll
    for (int c = 0; c < 16; ++c) f[h * 16 + c] = o[c];

    float R[9], T[3];
    #pragma unroll
    for (int z = 0; z < 9; ++z) R[z] = rot[(size_t)i * 9 + z];
    #pragma unroll
    for (int d = 0; d < 3; ++d) T[d] = trans[(size_t)i * 3 + d];

    #pragma unroll
    for (int p = 0; p < 8; ++p) {
        float g0 = o[16 + p * 3 + 0] - T[0];
        float g1 = o[16 + p * 3 + 1] - T[1];
        float g2 = o[16 + p * 3 + 2] - T[2];
        float xx = R[0] * g0 + R[3] * g1 + R[6] * g2;
        float yy = R[1] * g0 + R[4] * g1 + R[7] * g2;
        float zz = R[2] * g0 + R[5] * g1 + R[8] * g2;
        float dist = sqrtf(xx * xx + yy * yy + zz * zz + EPSm);
        f[192 + h * 8 + p] = xx;
        f[288 + h * 8 + p] = yy;
        f[384 + h * 8 + p] = zz;
        f[480 + h * 8 + p] = dist;
    }
}

// ---------------------------------------------------------------------------
extern "C" void kernel_launch(void* const* d_in, const int* in_sizes, int n_in,
                              void* d_out, int out_size, void* d_ws, size_t ws_size,
                              hipStream_t stream)
{
    const float* s     = (const float*)d_in[0];
    const float* rot   = (const float*)d_in[1];
    const float* trans = (const float*)d_in[2];
    const float* mask  = (const float*)d_in[3];
    const float* Wq    = (const float*)d_in[4];
    const float* bq    = (const float*)d_in[5];
    const float* Wkv   = (const float*)d_in[6];
    const float* bkv   = (const float*)d_in[7];
    const float* Wqp   = (const float*)d_in[8];
    const float* bqp   = (const float*)d_in[9];
    const float* Wkvp  = (const float*)d_in[10];
    const float* bkvp  = (const float*)d_in[11];
    const float* hwv   = (const float*)d_in[12];
    const float* Wout  = (const float*)d_in[13];
    const float* bout  = (const float*)d_in[14];
    float* out = (float*)d_out;
    float* ws  = (float*)d_ws;

    if (ws_size < (size_t)WS_FLOATS * sizeof(float)) return;

    float* Wall  = ws + OFF_WALL;
    float* ball  = ws + OFF_BALL;
    float* Pall  = ws + OFF_PALL;
    float* qpts  = ws + OFF_QPTS;
    float* q2    = ws + OFF_Q2;
    float* KPT   = ws + OFF_KPT;
    float* VPT   = ws + OFF_VPT;
    float* K2T   = ws + OFF_K2T;
    float* feats = ws + OFF_FEATS;
    float* part0 = ws + OFF_P0;
    float* part1 = ws + OFF_P1;

    concat_w<<<dim3(1728), 256, 0, stream>>>(Wq, Wkv, Wqp, Wkvp,
                                             bq, bkv, bqp, bkvp, Wall, ball);

    gemm_bt<<<dim3(1152 / 64, 2048 / 64), 256, 0, stream>>>(
        s, Wall, ball, Pall, 2048, 1152, 384);

    rotate_pack<<<dim3(96), 256, 0, stream>>>(Pall, rot, trans,
                                              qpts, q2, KPT, VPT, K2T);

    attn_part<<<dim3(768), 256, 0, stream>>>(
        Pall, qpts, q2, KPT, VPT, K2T, mask, hwv, part0, part1);

    attn_fin<<<dim3(96), 256, 0, stream>>>(part0, part1, rot, trans, feats);

    gemm_bt<<<dim3(384 / 64, 2048 / 64), 256, 0, stream>>>(
        feats, Wout, bout, out, 2048, 384, 576);
}

// Round 6
// 223.310 us; speedup vs baseline: 35.0855x; 1.2767x over previous
//
#include <hip/hip_runtime.h>
#include <hip/hip_bf16.h>
#include <cstdint>
#include <cstddef>

// Problem constants
#define Hh    12
#define Nseq  2048
#define PSTR  1152      // concat projection width: 192 q | 384 kv | 144 qp | 432 kvp
#define EPSm  1e-8f
#define MASKV 1024.0f   // mask sentinel: (mi*M)*mj + (-M)*1 == 0 exactly when masks==1

typedef unsigned short ushort_t;
typedef __attribute__((ext_vector_type(8))) short bf8_t;   // 8 bf16 (4 VGPRs)
typedef __attribute__((ext_vector_type(4))) float f4_t;    // MFMA C/D

// ws offsets (floats). Total 6,341,760 fl = 25.4 MB <= proven 29.1 MB budget.
#define OFF_WALL  0               // 1152*384
#define OFF_BALL  442368          // 1152
#define OFF_PALL  443520          // 2048*1152
#define OFF_AAUG  2802816         // bf16 [12][2048][32]  (393216 fl)
#define OFF_KAUG  3196032         // bf16 [12][2048][32]  (393216 fl)
#define OFF_VAUG  3589248         // bf16 [12][48][2048]  (589824 fl)
#define OFF_PART  4179072         // fp32 [12][2048][40]  (983040 fl)
#define OFF_FEATS 5162112         // fp32 [2048][576]     (1179648 fl)
#define WS_FLOATS 6341760

__device__ __forceinline__ ushort_t bfr(float x) {   // fp32 -> bf16 bits, RNE
    union { float f; uint32_t u; } v; v.f = x;
    uint32_t r = v.u + 0x7FFFu + ((v.u >> 16) & 1u);
    return (ushort_t)(r >> 16);
}

// ---------------------------------------------------------------------------
// Concat weights/biases (verified r4/r5).
// ---------------------------------------------------------------------------
__global__ __launch_bounds__(256) void concat_w(
    const float* __restrict__ Wq, const float* __restrict__ Wkv,
    const float* __restrict__ Wqp, const float* __restrict__ Wkvp,
    const float* __restrict__ bq, const float* __restrict__ bkv,
    const float* __restrict__ bqp, const float* __restrict__ bkvp,
    float* __restrict__ Wall, float* __restrict__ ball)
{
    int idx = blockIdx.x * 256 + threadIdx.x;
    if (idx < 1152 * 384) {
        int r = idx / 384, c = idx % 384;
        float v;
        if (r < 192)      v = Wq [(size_t)r * 384 + c];
        else if (r < 576) v = Wkv[(size_t)(r - 192) * 384 + c];
        else if (r < 720) v = Wqp[(size_t)(r - 576) * 384 + c];
        else              v = Wkvp[(size_t)(r - 720) * 384 + c];
        Wall[idx] = v;
    }
    if (idx < 1152) {
        float v;
        if (idx < 192)      v = bq[idx];
        else if (idx < 576) v = bkv[idx - 192];
        else if (idx < 720) v = bqp[idx - 576];
        else                v = bkvp[idx - 720];
        ball[idx] = v;
    }
}

// ---------------------------------------------------------------------------
// fp32 GEMM, verified r4/r5. C[m][n] = sum_k A[m][k]*W[n][k] + bias[n].
// ---------------------------------------------------------------------------
__global__ __launch_bounds__(256) void gemm_bt(
    const float* __restrict__ A, const float* __restrict__ W,
    const float* __restrict__ bias, float* __restrict__ Cm,
    int M, int Nn, int K)
{
    __shared__ float As[16][68];
    __shared__ float Bs[16][68];
    const int bm = blockIdx.y * 64;
    const int bn = blockIdx.x * 64;
    const int t  = threadIdx.x;
    const int tx = t & 15;
    const int ty = t >> 4;

    float acc[4][4] = {};

    for (int k0 = 0; k0 < K; k0 += 16) {
        #pragma unroll
        for (int u = 0; u < 4; ++u) {
            int idx = t + u * 256;
            int m = idx >> 4, k = idx & 15;
            As[k][m] = A[(size_t)(bm + m) * K + k0 + k];
            Bs[k][m] = W[(size_t)(bn + m) * K + k0 + k];
        }
        __syncthreads();
        #pragma unroll
        for (int k = 0; k < 16; ++k) {
            float4 av = *(const float4*)&As[k][ty * 4];
            float4 bv = *(const float4*)&Bs[k][tx * 4];
            float a[4] = {av.x, av.y, av.z, av.w};
            float b[4] = {bv.x, bv.y, bv.z, bv.w};
            #pragma unroll
            for (int i2 = 0; i2 < 4; ++i2)
                #pragma unroll
                for (int j2 = 0; j2 < 4; ++j2)
                    acc[i2][j2] = fmaf(a[i2], b[j2], acc[i2][j2]);
        }
        __syncthreads();
    }

    const float* bp = bias + bn + tx * 4;
    float4 bb = *(const float4*)bp;
    #pragma unroll
    for (int i2 = 0; i2 < 4; ++i2) {
        float4 o;
        o.x = acc[i2][0] + bb.x;
        o.y = acc[i2][1] + bb.y;
        o.z = acc[i2][2] + bb.z;
        o.w = acc[i2][3] + bb.w;
        *(float4*)&Cm[(size_t)(bm + ty * 4 + i2) * Nn + bn + tx * 4] = o;
    }
}

// ---------------------------------------------------------------------------
// Build augmented bf16 operands for MFMA attention. One thread per (h,n).
// logit(i,j) = Aaug[i] . Kaug[j]  (32-dim):
//   [0:16)  q*scale_a        .  k
//   [16:28) qp*2whw          .  kp
//   28      -whw             .  k2
//   29      -whw*q2          .  1
//   30      mi*MASKV         .  mj
//   31      -MASKV           .  1
// VaugT[h][c][j]: c 0-15 v, 16-39 vpts, 40 ones (L column), 41-47 zero.
// Point rotation math verbatim from verified rotate_pack (r5).
// ---------------------------------------------------------------------------
__global__ __launch_bounds__(256) void pack_aug(
    const float* __restrict__ Pall, const float* __restrict__ rot,
    const float* __restrict__ trans, const float* __restrict__ mask,
    const float* __restrict__ hwv,
    ushort_t* __restrict__ AU, ushort_t* __restrict__ KU,
    ushort_t* __restrict__ VU)
{
    int idx = blockIdx.x * 256 + threadIdx.x;    // h*2048 + n
    if (idx >= Hh * Nseq) return;
    int h = idx >> 11, n = idx & 2047;

    const float whw = 0.5f * logf(1.0f + expf(hwv[h])) * 0.13608276348795434f;
    const float scale_a = 0.14433756729740643f;   // sqrt(1/48)

    float R[9], T[3];
    #pragma unroll
    for (int z = 0; z < 9; ++z) R[z] = rot[(size_t)n * 9 + z];
    #pragma unroll
    for (int d = 0; d < 3; ++d) T[d] = trans[(size_t)n * 3 + d];

    const float* base = Pall + (size_t)n * PSTR;

    float qpv[12], q2 = 0.f;
    #pragma unroll
    for (int p = 0; p < 4; ++p) {
        float r0 = base[576 +   0 + h * 4 + p];
        float r1 = base[576 +  48 + h * 4 + p];
        float r2 = base[576 +  96 + h * 4 + p];
        #pragma unroll
        for (int d = 0; d < 3; ++d) {
            float o = R[d*3+0]*r0 + R[d*3+1]*r1 + R[d*3+2]*r2 + T[d];
            qpv[p * 3 + d] = o;
            q2 += o * o;
        }
    }

    float kpv[12], vpv[24], k2 = 0.f;
    #pragma unroll
    for (int pt = 0; pt < 12; ++pt) {
        float r0 = base[720 +   0 + h * 12 + pt];
        float r1 = base[720 + 144 + h * 12 + pt];
        float r2 = base[720 + 288 + h * 12 + pt];
        #pragma unroll
        for (int d = 0; d < 3; ++d) {
            float o = R[d*3+0]*r0 + R[d*3+1]*r1 + R[d*3+2]*r2 + T[d];
            if (pt < 4) { kpv[pt * 3 + d] = o; k2 += o * o; }
            else        { vpv[(pt - 4) * 3 + d] = o; }
        }
    }

    const float mi = mask[n];

    __align__(16) ushort_t a32[32];
    #pragma unroll
    for (int c = 0; c < 16; ++c) a32[c] = bfr(base[h * 16 + c] * scale_a);
    #pragma unroll
    for (int z = 0; z < 12; ++z) a32[16 + z] = bfr(qpv[z] * (2.0f * whw));
    a32[28] = bfr(-whw);
    a32[29] = bfr(-whw * q2);
    a32[30] = bfr(mi * MASKV);
    a32[31] = bfr(-MASKV);
    ushort_t* adst = AU + ((size_t)h * Nseq + n) * 32;
    #pragma unroll
    for (int u = 0; u < 4; ++u) ((uint4*)adst)[u] = ((const uint4*)a32)[u];

    const float* kvrow = base + 192 + h * 32;   // k[16] then v[16]
    __align__(16) ushort_t k32[32];
    #pragma unroll
    for (int c = 0; c < 16; ++c) k32[c] = bfr(kvrow[c]);
    #pragma unroll
    for (int z = 0; z < 12; ++z) k32[16 + z] = bfr(kpv[z]);
    k32[28] = bfr(k2);
    k32[29] = 0x3F80;           // 1.0 bf16
    k32[30] = bfr(mi);          // mj (same n)
    k32[31] = 0x3F80;
    ushort_t* kdst = KU + ((size_t)h * Nseq + n) * 32;
    #pragma unroll
    for (int u = 0; u < 4; ++u) ((uint4*)kdst)[u] = ((const uint4*)k32)[u];

    // VaugT: coalesced across n (lanes = consecutive n)
    ushort_t* vb = VU + (size_t)h * 48 * Nseq + n;
    #pragma unroll
    for (int c = 0; c < 16; ++c) vb[(size_t)c * Nseq] = bfr(kvrow[16 + c]);
    #pragma unroll
    for (int z = 0; z < 24; ++z) vb[(size_t)(16 + z) * Nseq] = bfr(vpv[z]);
    vb[(size_t)40 * Nseq] = 0x3F80;
    #pragma unroll
    for (int c = 41; c < 48; ++c) vb[(size_t)c * Nseq] = 0;
}

// ---------------------------------------------------------------------------
// MFMA flash attention. Grid 384 = 12 h x 32 i-blocks(64). 4 waves; wave w
// owns i-rows [i0+w*16, +16) x ALL j. Per 32-j tile: 2 QK MFMAs -> exp ->
// wave-private LDS round-trip (P to A-layout, m120 pattern) -> 3 PV MFMAs
// into fp32 acc (48 cols: v16 | vpts24 | L @40 | pad). No __syncthreads.
// Output: part[h][i][40] = softmax-normalized (o16 | opt24).
// ---------------------------------------------------------------------------
__global__ __launch_bounds__(256) void attn_mfma(
    const ushort_t* __restrict__ AU, const ushort_t* __restrict__ KU,
    const ushort_t* __restrict__ VU, float* __restrict__ part)
{
    __shared__ short Pt[4][16][40];   // 5120 B; 40-stride => <=2-way conflicts

    const int b    = blockIdx.x;
    const int h    = b >> 5;
    const int iblk = b & 31;
    const int t    = threadIdx.x;
    const int w    = t >> 6;
    const int lane = t & 63;
    const int m    = lane & 15;
    const int quad = lane >> 4;
    const int i0   = iblk * 64 + w * 16;

    // A-frag: lane m holds Aaug[i0+m][quad*8 .. +8]  (A[m][k] layout)
    bf8_t afrag = *(const bf8_t*)(AU + ((size_t)h * Nseq + i0 + m) * 32 + quad * 8);

    f4_t acc0 = {0.f, 0.f, 0.f, 0.f};
    f4_t acc1 = {0.f, 0.f, 0.f, 0.f};
    f4_t acc2 = {0.f, 0.f, 0.f, 0.f};

    const ushort_t* kbase  = KU + ((size_t)h * Nseq + m) * 32 + quad * 8;
    const ushort_t* vbase0 = VU + ((size_t)h * 48 +  0 + m) * Nseq + quad * 8;
    const ushort_t* vbase1 = VU + ((size_t)h * 48 + 16 + m) * Nseq + quad * 8;
    const ushort_t* vbase2 = VU + ((size_t)h * 48 + 32 + m) * Nseq + quad * 8;

    for (int jt = 0; jt < 64; ++jt) {
        const int j0 = jt * 32;
        // B-frags for QK: lane n=m holds Kaug[j0(+16)+n][quad*8 .. +8]
        bf8_t kb0 = *(const bf8_t*)(kbase + (size_t)j0 * 32);
        bf8_t kb1 = *(const bf8_t*)(kbase + (size_t)(j0 + 16) * 32);
        f4_t s0 = __builtin_amdgcn_mfma_f32_16x16x32_bf16(afrag, kb0,
                     (f4_t){0.f, 0.f, 0.f, 0.f}, 0, 0, 0);
        f4_t s1 = __builtin_amdgcn_mfma_f32_16x16x32_bf16(afrag, kb1,
                     (f4_t){0.f, 0.f, 0.f, 0.f}, 0, 0, 0);
        // exp + store P tile (C/D layout: row=quad*4+reg, col=lane&15)
        #pragma unroll
        for (int r = 0; r < 4; ++r) {
            Pt[w][quad * 4 + r][m]      = (short)bfr(__expf(s0[r]));
            Pt[w][quad * 4 + r][16 + m] = (short)bfr(__expf(s1[r]));
        }
        // wave-private LDS; lockstep wave64 + compiler lgkm waits order this
        bf8_t pf = *(const bf8_t*)&Pt[w][m][quad * 8];   // A[m][k] layout
        bf8_t v0 = *(const bf8_t*)(vbase0 + j0);
        bf8_t v1 = *(const bf8_t*)(vbase1 + j0);
        bf8_t v2 = *(const bf8_t*)(vbase2 + j0);
        acc0 = __builtin_amdgcn_mfma_f32_16x16x32_bf16(pf, v0, acc0, 0, 0, 0);
        acc1 = __builtin_amdgcn_mfma_f32_16x16x32_bf16(pf, v1, acc1, 0, 0, 0);
        acc2 = __builtin_amdgcn_mfma_f32_16x16x32_bf16(pf, v2, acc2, 0, 0, 0);
    }

    // L = col 40 = block-2 col 8: broadcast within row (same quad, lane m=8)
    #pragma unroll
    for (int r = 0; r < 4; ++r) {
        float L   = __shfl(acc2[r], (lane & 48) | 8, 64);
        float inv = 1.0f / L;
        float* dst = part + ((size_t)h * Nseq + i0 + quad * 4 + r) * 40;
        dst[m]      = acc0[r] * inv;
        dst[16 + m] = acc1[r] * inv;
        if (m < 8) dst[32 + m] = acc2[r] * inv;
    }
}

// ---------------------------------------------------------------------------
// Epilogue: read normalized (o|o_pt), inverse-rotate, dists, write feats.
// Math verbatim from verified r3/r5.
// ---------------------------------------------------------------------------
__global__ __launch_bounds__(256) void attn_fin(
    const float* __restrict__ part, const float* __restrict__ rot,
    const float* __restrict__ trans, float* __restrict__ feats)
{
    int idx = blockIdx.x * 256 + threadIdx.x;   // i*12 + h
    if (idx >= Nseq * Hh) return;
    int i = idx / Hh, h = idx % Hh;

    const float* p = part + ((size_t)h * Nseq + i) * 40;
    float o[40];
    #pragma unroll
    for (int z = 0; z < 40; ++z) o[z] = p[z];

    float* f = feats + (size_t)i * 576;
    #pragma unroll
    for (int c = 0; c < 16; ++c) f[h * 16 + c] = o[c];

    float R[9], T[3];
    #pragma unroll
    for (int z = 0; z < 9; ++z) R[z] = rot[(size_t)i * 9 + z];
    #pragma unroll
    for (int d = 0; d < 3; ++d) T[d] = trans[(size_t)i * 3 + d];

    #pragma unroll
    for (int p8 = 0; p8 < 8; ++p8) {
        float g0 = o[16 + p8 * 3 + 0] - T[0];
        float g1 = o[16 + p8 * 3 + 1] - T[1];
        float g2 = o[16 + p8 * 3 + 2] - T[2];
        float xx = R[0] * g0 + R[3] * g1 + R[6] * g2;
        float yy = R[1] * g0 + R[4] * g1 + R[7] * g2;
        float zz = R[2] * g0 + R[5] * g1 + R[8] * g2;
        float dist = sqrtf(xx * xx + yy * yy + zz * zz + EPSm);
        f[192 + h * 8 + p8] = xx;
        f[288 + h * 8 + p8] = yy;
        f[384 + h * 8 + p8] = zz;
        f[480 + h * 8 + p8] = dist;
    }
}

// ---------------------------------------------------------------------------
extern "C" void kernel_launch(void* const* d_in, const int* in_sizes, int n_in,
                              void* d_out, int out_size, void* d_ws, size_t ws_size,
                              hipStream_t stream)
{
    const float* s     = (const float*)d_in[0];
    const float* rot   = (const float*)d_in[1];
    const float* trans = (const float*)d_in[2];
    const float* mask  = (const float*)d_in[3];
    const float* Wq    = (const float*)d_in[4];
    const float* bq    = (const float*)d_in[5];
    const float* Wkv   = (const float*)d_in[6];
    const float* bkv   = (const float*)d_in[7];
    const float* Wqp   = (const float*)d_in[8];
    const float* bqp   = (const float*)d_in[9];
    const float* Wkvp  = (const float*)d_in[10];
    const float* bkvp  = (const float*)d_in[11];
    const float* hwv   = (const float*)d_in[12];
    const float* Wout  = (const float*)d_in[13];
    const float* bout  = (const float*)d_in[14];
    float* out = (float*)d_out;
    float* ws  = (float*)d_ws;

    if (ws_size < (size_t)WS_FLOATS * sizeof(float)) return;

    float*    Wall  = ws + OFF_WALL;
    float*    ball  = ws + OFF_BALL;
    float*    Pall  = ws + OFF_PALL;
    ushort_t* AU    = (ushort_t*)(ws + OFF_AAUG);
    ushort_t* KU    = (ushort_t*)(ws + OFF_KAUG);
    ushort_t* VU    = (ushort_t*)(ws + OFF_VAUG);
    float*    partb = ws + OFF_PART;
    float*    feats = ws + OFF_FEATS;

    concat_w<<<dim3(1728), 256, 0, stream>>>(Wq, Wkv, Wqp, Wkvp,
                                             bq, bkv, bqp, bkvp, Wall, ball);

    gemm_bt<<<dim3(1152 / 64, 2048 / 64), 256, 0, stream>>>(
        s, Wall, ball, Pall, 2048, 1152, 384);

    pack_aug<<<dim3(96), 256, 0, stream>>>(Pall, rot, trans, mask, hwv,
                                           AU, KU, VU);

    attn_mfma<<<dim3(384), 256, 0, stream>>>(AU, KU, VU, partb);

    attn_fin<<<dim3(96), 256, 0, stream>>>(partb, rot, trans, feats);

    gemm_bt<<<dim3(384 / 64, 2048 / 64), 256, 0, stream>>>(
        feats, Wout, bout, out, 2048, 384, 576);
}

// Round 7
// 172.480 us; speedup vs baseline: 45.4250x; 1.2947x over previous
//
#include <hip/hip_runtime.h>
#include <hip/hip_bf16.h>
#include <cstdint>
#include <cstddef>

// Problem constants
#define Hh    12
#define Nseq  2048
#define PSTR  1152      // concat projection width: 192 q | 384 kv | 144 qp | 432 kvp
#define EPSm  1e-8f
#define MASKV 1024.0f   // mask sentinel: (mi*M)*mj + (-M)*1 == 0 exactly when masks==1

typedef unsigned short ushort_t;
typedef __attribute__((ext_vector_type(8))) short bf8_t;   // 8 bf16 (4 VGPRs)
typedef __attribute__((ext_vector_type(4))) float f4_t;    // MFMA C/D

// ws offsets (floats). Total 6,034,560 fl = 24.1 MB <= proven 29.1 MB budget.
#define OFF_PALL   0         // fp32 [2048][1152]        (2359296)
#define OFF_WALLB  2359296   // bf16 [1152][384]         (221184 fl)
#define OFF_BALL   2580480   // fp32 [1152]              (1152)
#define OFF_SB     2581632   // bf16 [2048][384]         (393216 fl)
#define OFF_WOUTB  2974848   // bf16 [384][576]          (110592 fl)
#define OFF_FEATSB 3085440   // bf16 [2048][576]         (589824 fl)
#define OFF_AU     3675264   // bf16 [12][2048][32]      (393216 fl)
#define OFF_KU     4068480   // bf16 [12][2048][32]      (393216 fl)
#define OFF_VU     4461696   // bf16 [12][48][2048]      (589824 fl)
#define OFF_PART   5051520   // fp32 [12][2048][40]      (983040 fl)
#define WS_FLOATS  6034560

__device__ __forceinline__ ushort_t bfr(float x) {   // fp32 -> bf16 bits, RNE
    union { float f; uint32_t u; } v; v.f = x;
    uint32_t r = v.u + 0x7FFFu + ((v.u >> 16) & 1u);
    return (ushort_t)(r >> 16);
}

// ---------------------------------------------------------------------------
// prep: concat weights -> bf16 Wall, biases -> fp32 ball, s -> bf16,
// Wout -> bf16. Grid 3072 x 256 covers the largest section (s: 786432).
// ---------------------------------------------------------------------------
__global__ __launch_bounds__(256) void prep(
    const float* __restrict__ s, const float* __restrict__ Wout,
    const float* __restrict__ Wq, const float* __restrict__ Wkv,
    const float* __restrict__ Wqp, const float* __restrict__ Wkvp,
    const float* __restrict__ bq, const float* __restrict__ bkv,
    const float* __restrict__ bqp, const float* __restrict__ bkvp,
    ushort_t* __restrict__ Wallb, float* __restrict__ ball,
    ushort_t* __restrict__ sb, ushort_t* __restrict__ Woutb)
{
    int idx = blockIdx.x * 256 + threadIdx.x;
    if (idx < 1152 * 384) {
        int r = idx / 384, c = idx % 384;
        float v;
        if (r < 192)      v = Wq [(size_t)r * 384 + c];
        else if (r < 576) v = Wkv[(size_t)(r - 192) * 384 + c];
        else if (r < 720) v = Wqp[(size_t)(r - 576) * 384 + c];
        else              v = Wkvp[(size_t)(r - 720) * 384 + c];
        Wallb[idx] = bfr(v);
    }
    if (idx < 1152) {
        float v;
        if (idx < 192)      v = bq[idx];
        else if (idx < 576) v = bkv[idx - 192];
        else if (idx < 720) v = bqp[idx - 576];
        else                v = bkvp[idx - 720];
        ball[idx] = v;
    }
    if (idx < 2048 * 384) sb[idx] = bfr(s[idx]);
    if (idx < 384 * 576)  Woutb[idx] = bfr(Wout[idx]);
}

// ---------------------------------------------------------------------------
// bf16 MFMA GEMM: C[m][n] = sum_k A[m][k]*W[n][k] + bias[n], fp32 out.
// BM=BN=128, BK=32, 256 thr = 4 waves (2x2 of 64x64), 4x4 MFMA 16x16x32 each.
// Fragment conventions identical to the r6-verified attention kernel.
// ---------------------------------------------------------------------------
__global__ __launch_bounds__(256) void gemm_mfma(
    const ushort_t* __restrict__ A, const ushort_t* __restrict__ W,
    const float* __restrict__ bias, float* __restrict__ C,
    int M, int Nn, int K)
{
    __shared__ ushort_t As[128][40];   // +8 pad: b128 reads <=2-way conflicts
    __shared__ ushort_t Bs[128][40];

    const int bm = blockIdx.y * 128;
    const int bn = blockIdx.x * 128;
    const int t  = threadIdx.x;
    const int w  = t >> 6, lane = t & 63;
    const int m  = lane & 15, quad = lane >> 4;
    const int wm = (w >> 1) * 64, wn = (w & 1) * 64;

    f4_t acc[4][4];
    #pragma unroll
    for (int i2 = 0; i2 < 4; ++i2)
        #pragma unroll
        for (int j2 = 0; j2 < 4; ++j2)
            acc[i2][j2] = (f4_t){0.f, 0.f, 0.f, 0.f};

    for (int k0 = 0; k0 < K; k0 += 32) {
        #pragma unroll
        for (int u = 0; u < 2; ++u) {
            int c = t + u * 256;            // 0..511
            int r = c >> 2, kk = (c & 3) * 8;
            *(uint4*)&As[r][kk] = *(const uint4*)&A[(size_t)(bm + r) * K + k0 + kk];
            *(uint4*)&Bs[r][kk] = *(const uint4*)&W[(size_t)(bn + r) * K + k0 + kk];
        }
        __syncthreads();
        bf8_t af[4], bf[4];
        #pragma unroll
        for (int x = 0; x < 4; ++x) {
            af[x] = *(const bf8_t*)&As[wm + x * 16 + m][quad * 8];
            bf[x] = *(const bf8_t*)&Bs[wn + x * 16 + m][quad * 8];
        }
        #pragma unroll
        for (int i2 = 0; i2 < 4; ++i2)
            #pragma unroll
            for (int j2 = 0; j2 < 4; ++j2)
                acc[i2][j2] = __builtin_amdgcn_mfma_f32_16x16x32_bf16(
                    af[i2], bf[j2], acc[i2][j2], 0, 0, 0);
        __syncthreads();
    }

    // C/D layout (r6-verified): col = lane&15 (W-row n), row = quad*4+r (A-row)
    #pragma unroll
    for (int j2 = 0; j2 < 4; ++j2) {
        int col = bn + wn + j2 * 16 + m;
        float bb = bias[col];
        #pragma unroll
        for (int i2 = 0; i2 < 4; ++i2) {
            #pragma unroll
            for (int r = 0; r < 4; ++r) {
                int row = bm + wm + i2 * 16 + quad * 4 + r;
                C[(size_t)row * Nn + col] = acc[i2][j2][r] + bb;
            }
        }
    }
}

// ---------------------------------------------------------------------------
// Build augmented bf16 operands for MFMA attention (verified r6).
// logit(i,j) = Aaug[i].Kaug[j] (32-dim); VaugT[h][c][j] c: v16|vpts24|1@40|0.
// ---------------------------------------------------------------------------
__global__ __launch_bounds__(256) void pack_aug(
    const float* __restrict__ Pall, const float* __restrict__ rot,
    const float* __restrict__ trans, const float* __restrict__ mask,
    const float* __restrict__ hwv,
    ushort_t* __restrict__ AU, ushort_t* __restrict__ KU,
    ushort_t* __restrict__ VU)
{
    int idx = blockIdx.x * 256 + threadIdx.x;    // h*2048 + n
    if (idx >= Hh * Nseq) return;
    int h = idx >> 11, n = idx & 2047;

    const float whw = 0.5f * logf(1.0f + expf(hwv[h])) * 0.13608276348795434f;
    const float scale_a = 0.14433756729740643f;   // sqrt(1/48)

    float R[9], T[3];
    #pragma unroll
    for (int z = 0; z < 9; ++z) R[z] = rot[(size_t)n * 9 + z];
    #pragma unroll
    for (int d = 0; d < 3; ++d) T[d] = trans[(size_t)n * 3 + d];

    const float* base = Pall + (size_t)n * PSTR;

    float qpv[12], q2 = 0.f;
    #pragma unroll
    for (int p = 0; p < 4; ++p) {
        float r0 = base[576 +   0 + h * 4 + p];
        float r1 = base[576 +  48 + h * 4 + p];
        float r2 = base[576 +  96 + h * 4 + p];
        #pragma unroll
        for (int d = 0; d < 3; ++d) {
            float o = R[d*3+0]*r0 + R[d*3+1]*r1 + R[d*3+2]*r2 + T[d];
            qpv[p * 3 + d] = o;
            q2 += o * o;
        }
    }

    float kpv[12], vpv[24], k2 = 0.f;
    #pragma unroll
    for (int pt = 0; pt < 12; ++pt) {
        float r0 = base[720 +   0 + h * 12 + pt];
        float r1 = base[720 + 144 + h * 12 + pt];
        float r2 = base[720 + 288 + h * 12 + pt];
        #pragma unroll
        for (int d = 0; d < 3; ++d) {
            float o = R[d*3+0]*r0 + R[d*3+1]*r1 + R[d*3+2]*r2 + T[d];
            if (pt < 4) { kpv[pt * 3 + d] = o; k2 += o * o; }
            else        { vpv[(pt - 4) * 3 + d] = o; }
        }
    }

    const float mi = mask[n];

    __align__(16) ushort_t a32[32];
    #pragma unroll
    for (int c = 0; c < 16; ++c) a32[c] = bfr(base[h * 16 + c] * scale_a);
    #pragma unroll
    for (int z = 0; z < 12; ++z) a32[16 + z] = bfr(qpv[z] * (2.0f * whw));
    a32[28] = bfr(-whw);
    a32[29] = bfr(-whw * q2);
    a32[30] = bfr(mi * MASKV);
    a32[31] = bfr(-MASKV);
    ushort_t* adst = AU + ((size_t)h * Nseq + n) * 32;
    #pragma unroll
    for (int u = 0; u < 4; ++u) ((uint4*)adst)[u] = ((const uint4*)a32)[u];

    const float* kvrow = base + 192 + h * 32;   // k[16] then v[16]
    __align__(16) ushort_t k32[32];
    #pragma unroll
    for (int c = 0; c < 16; ++c) k32[c] = bfr(kvrow[c]);
    #pragma unroll
    for (int z = 0; z < 12; ++z) k32[16 + z] = bfr(kpv[z]);
    k32[28] = bfr(k2);
    k32[29] = 0x3F80;           // 1.0 bf16
    k32[30] = bfr(mi);          // mj (same n)
    k32[31] = 0x3F80;
    ushort_t* kdst = KU + ((size_t)h * Nseq + n) * 32;
    #pragma unroll
    for (int u = 0; u < 4; ++u) ((uint4*)kdst)[u] = ((const uint4*)k32)[u];

    ushort_t* vb = VU + (size_t)h * 48 * Nseq + n;
    #pragma unroll
    for (int c = 0; c < 16; ++c) vb[(size_t)c * Nseq] = bfr(kvrow[16 + c]);
    #pragma unroll
    for (int z = 0; z < 24; ++z) vb[(size_t)(16 + z) * Nseq] = bfr(vpv[z]);
    vb[(size_t)40 * Nseq] = 0x3F80;
    #pragma unroll
    for (int c = 41; c < 48; ++c) vb[(size_t)c * Nseq] = 0;
}

// ---------------------------------------------------------------------------
// MFMA flash attention v2 (occupancy fix). Grid 1536 = 12 h x 128 i-blocks
// of 16 rows. 4 waves: wave w owns j in [w*512, +512) = 16 j-tiles of 32.
// Per-tile math verbatim from r6-verified kernel. Plain-sum partials merged
// in LDS (L = col 40), normalize, write part[h][i][40].
// ---------------------------------------------------------------------------
__global__ __launch_bounds__(256) void attn_mfma(
    const ushort_t* __restrict__ AU, const ushort_t* __restrict__ KU,
    const ushort_t* __restrict__ VU, float* __restrict__ part)
{
    __shared__ short Pt[4][16][40];    // 5120 B, wave-private tiles
    __shared__ float red[4][16][48];   // 12288 B, merge buffer

    const int b    = blockIdx.x;
    const int h    = b >> 7;           // 0..11
    const int ib   = b & 127;          // 0..127
    const int t    = threadIdx.x;
    const int w    = t >> 6;
    const int lane = t & 63;
    const int m    = lane & 15;
    const int quad = lane >> 4;
    const int i0   = ib * 16;

    bf8_t afrag = *(const bf8_t*)(AU + ((size_t)h * Nseq + i0 + m) * 32 + quad * 8);

    f4_t acc0 = {0.f, 0.f, 0.f, 0.f};
    f4_t acc1 = {0.f, 0.f, 0.f, 0.f};
    f4_t acc2 = {0.f, 0.f, 0.f, 0.f};

    const int jbeg = w * 512;
    const ushort_t* kbase  = KU + ((size_t)h * Nseq + jbeg + m) * 32 + quad * 8;
    const ushort_t* vbase0 = VU + ((size_t)h * 48 +  0 + m) * Nseq + jbeg + quad * 8;
    const ushort_t* vbase1 = VU + ((size_t)h * 48 + 16 + m) * Nseq + jbeg + quad * 8;
    const ushort_t* vbase2 = VU + ((size_t)h * 48 + 32 + m) * Nseq + jbeg + quad * 8;

    for (int jt = 0; jt < 16; ++jt) {
        const int j0 = jt * 32;
        bf8_t kb0 = *(const bf8_t*)(kbase + (size_t)j0 * 32);
        bf8_t kb1 = *(const bf8_t*)(kbase + (size_t)(j0 + 16) * 32);
        f4_t s0 = __builtin_amdgcn_mfma_f32_16x16x32_bf16(afrag, kb0,
                     (f4_t){0.f, 0.f, 0.f, 0.f}, 0, 0, 0);
        f4_t s1 = __builtin_amdgcn_mfma_f32_16x16x32_bf16(afrag, kb1,
                     (f4_t){0.f, 0.f, 0.f, 0.f}, 0, 0, 0);
        #pragma unroll
        for (int r = 0; r < 4; ++r) {
            Pt[w][quad * 4 + r][m]      = (short)bfr(__expf(s0[r]));
            Pt[w][quad * 4 + r][16 + m] = (short)bfr(__expf(s1[r]));
        }
        bf8_t pf = *(const bf8_t*)&Pt[w][m][quad * 8];   // wave-lockstep RT
        bf8_t v0 = *(const bf8_t*)(vbase0 + j0);
        bf8_t v1 = *(const bf8_t*)(vbase1 + j0);
        bf8_t v2 = *(const bf8_t*)(vbase2 + j0);
        acc0 = __builtin_amdgcn_mfma_f32_16x16x32_bf16(pf, v0, acc0, 0, 0, 0);
        acc1 = __builtin_amdgcn_mfma_f32_16x16x32_bf16(pf, v1, acc1, 0, 0, 0);
        acc2 = __builtin_amdgcn_mfma_f32_16x16x32_bf16(pf, v2, acc2, 0, 0, 0);
    }

    // dump per-wave partials (C/D layout: row=quad*4+r, col=m)
    #pragma unroll
    for (int r = 0; r < 4; ++r) {
        red[w][quad * 4 + r][m]      = acc0[r];
        red[w][quad * 4 + r][16 + m] = acc1[r];
        red[w][quad * 4 + r][32 + m] = acc2[r];
    }
    __syncthreads();

    // sum 4 waves: 768 entries, 3 per thread; disjoint read/write on red[0]
    #pragma unroll
    for (int u = 0; u < 3; ++u) {
        int e = t + u * 256;
        int r = e / 48, c = e % 48;
        red[0][r][c] = red[0][r][c] + red[1][r][c] + red[2][r][c] + red[3][r][c];
    }
    __syncthreads();

    // normalize by L (col 40), write 640 outputs
    #pragma unroll
    for (int u = 0; u < 3; ++u) {
        int e = t + u * 256;
        if (e < 640) {
            int r = e / 40, c = e % 40;
            float L = red[0][r][40];
            part[((size_t)h * Nseq + i0 + r) * 40 + c] = red[0][r][c] / L;
        }
    }
}

// ---------------------------------------------------------------------------
// Epilogue: inverse-rotate o_pt, dists, write feats as bf16 (gemm2 operand).
// Math verbatim from r3/r5/r6-verified kernel.
// ---------------------------------------------------------------------------
__global__ __launch_bounds__(256) void attn_fin(
    const float* __restrict__ part, const float* __restrict__ rot,
    const float* __restrict__ trans, ushort_t* __restrict__ featsb)
{
    int idx = blockIdx.x * 256 + threadIdx.x;   // i*12 + h
    if (idx >= Nseq * Hh) return;
    int i = idx / Hh, h = idx % Hh;

    const float* p = part + ((size_t)h * Nseq + i) * 40;
    float o[40];
    #pragma unroll
    for (int z = 0; z < 40; ++z) o[z] = p[z];

    ushort_t* f = featsb + (size_t)i * 576;
    #pragma unroll
    for (int c = 0; c < 16; ++c) f[h * 16 + c] = bfr(o[c]);

    float R[9], T[3];
    #pragma unroll
    for (int z = 0; z < 9; ++z) R[z] = rot[(size_t)i * 9 + z];
    #pragma unroll
    for (int d = 0; d < 3; ++d) T[d] = trans[(size_t)i * 3 + d];

    #pragma unroll
    for (int p8 = 0; p8 < 8; ++p8) {
        float g0 = o[16 + p8 * 3 + 0] - T[0];
        float g1 = o[16 + p8 * 3 + 1] - T[1];
        float g2 = o[16 + p8 * 3 + 2] - T[2];
        float xx = R[0] * g0 + R[3] * g1 + R[6] * g2;
        float yy = R[1] * g0 + R[4] * g1 + R[7] * g2;
        float zz = R[2] * g0 + R[5] * g1 + R[8] * g2;
        float dist = sqrtf(xx * xx + yy * yy + zz * zz + EPSm);
        f[192 + h * 8 + p8] = bfr(xx);
        f[288 + h * 8 + p8] = bfr(yy);
        f[384 + h * 8 + p8] = bfr(zz);
        f[480 + h * 8 + p8] = bfr(dist);
    }
}

// ---------------------------------------------------------------------------
extern "C" void kernel_launch(void* const* d_in, const int* in_sizes, int n_in,
                              void* d_out, int out_size, void* d_ws, size_t ws_size,
                              hipStream_t stream)
{
    const float* s     = (const float*)d_in[0];
    const float* rot   = (const float*)d_in[1];
    const float* trans = (const float*)d_in[2];
    const float* mask  = (const float*)d_in[3];
    const float* Wq    = (const float*)d_in[4];
    const float* bq    = (const float*)d_in[5];
    const float* Wkv   = (const float*)d_in[6];
    const float* bkv   = (const float*)d_in[7];
    const float* Wqp   = (const float*)d_in[8];
    const float* bqp   = (const float*)d_in[9];
    const float* Wkvp  = (const float*)d_in[10];
    const float* bkvp  = (const float*)d_in[11];
    const float* hwv   = (const float*)d_in[12];
    const float* Wout  = (const float*)d_in[13];
    const float* bout  = (const float*)d_in[14];
    float* out = (float*)d_out;
    float* ws  = (float*)d_ws;

    if (ws_size < (size_t)WS_FLOATS * sizeof(float)) return;

    float*    Pall   = ws + OFF_PALL;
    ushort_t* Wallb  = (ushort_t*)(ws + OFF_WALLB);
    float*    ball   = ws + OFF_BALL;
    ushort_t* sb     = (ushort_t*)(ws + OFF_SB);
    ushort_t* Woutb  = (ushort_t*)(ws + OFF_WOUTB);
    ushort_t* featsb = (ushort_t*)(ws + OFF_FEATSB);
    ushort_t* AU     = (ushort_t*)(ws + OFF_AU);
    ushort_t* KU     = (ushort_t*)(ws + OFF_KU);
    ushort_t* VU     = (ushort_t*)(ws + OFF_VU);
    float*    partb  = ws + OFF_PART;

    prep<<<dim3(3072), 256, 0, stream>>>(s, Wout, Wq, Wkv, Wqp, Wkvp,
                                         bq, bkv, bqp, bkvp,
                                         Wallb, ball, sb, Woutb);

    gemm_mfma<<<dim3(1152 / 128, 2048 / 128), 256, 0, stream>>>(
        sb, Wallb, ball, Pall, 2048, 1152, 384);

    pack_aug<<<dim3(96), 256, 0, stream>>>(Pall, rot, trans, mask, hwv,
                                           AU, KU, VU);

    attn_mfma<<<dim3(1536), 256, 0, stream>>>(AU, KU, VU, partb);

    attn_fin<<<dim3(96), 256, 0, stream>>>(partb, rot, trans, featsb);

    gemm_mfma<<<dim3(384 / 128, 2048 / 128), 256, 0, stream>>>(
        featsb, Woutb, bout, out, 2048, 384, 576);
}

// Round 8
// 152.969 us; speedup vs baseline: 51.2190x; 1.1276x over previous
//
#include <hip/hip_runtime.h>
#include <hip/hip_bf16.h>
#include <cstdint>
#include <cstddef>

// Problem constants
#define Hh    12
#define Nseq  2048
#define PSTR  1152      // concat projection width: 192 q | 384 kv | 144 qp | 432 kvp
#define EPSm  1e-8f
#define MASKV 1024.0f   // (mi*M)*mj + (-M)*1 == 0 exactly when masks==1

typedef unsigned short ushort_t;
typedef __attribute__((ext_vector_type(8))) short bf8_t;   // 8 bf16 (4 VGPRs)
typedef __attribute__((ext_vector_type(4))) short s4_t;    // 4 bf16 (2 VGPRs)
typedef __attribute__((ext_vector_type(4))) float f4_t;    // MFMA C/D

// ws offsets (floats). Total 5,051,520 fl = 20.2 MB <= proven 29.1 MB budget.
#define OFF_PALL   0         // fp32 [2048][1152]
#define OFF_WALLB  2359296   // bf16 [1152][384]
#define OFF_BALL   2580480   // fp32 [1152]
#define OFF_SB     2581632   // bf16 [2048][384]
#define OFF_WOUTB  2974848   // bf16 [384][576]
#define OFF_FEATSB 3085440   // bf16 [2048][576]
#define OFF_AU     3675264   // bf16 [12][2048][32]
#define OFF_KU     4068480   // bf16 [12][2048][32]
#define OFF_VU     4461696   // bf16 [12][48][2048]
#define WS_FLOATS  5051520

__device__ __forceinline__ ushort_t bfr(float x) {   // fp32 -> bf16 bits, RNE
    union { float f; uint32_t u; } v; v.f = x;
    uint32_t r = v.u + 0x7FFFu + ((v.u >> 16) & 1u);
    return (ushort_t)(r >> 16);
}

// ---------------------------------------------------------------------------
// prep (verified r7): concat weights -> bf16 Wall, biases -> fp32, s/Wout bf16.
// ---------------------------------------------------------------------------
__global__ __launch_bounds__(256) void prep(
    const float* __restrict__ s, const float* __restrict__ Wout,
    const float* __restrict__ Wq, const float* __restrict__ Wkv,
    const float* __restrict__ Wqp, const float* __restrict__ Wkvp,
    const float* __restrict__ bq, const float* __restrict__ bkv,
    const float* __restrict__ bqp, const float* __restrict__ bkvp,
    ushort_t* __restrict__ Wallb, float* __restrict__ ball,
    ushort_t* __restrict__ sb, ushort_t* __restrict__ Woutb)
{
    int idx = blockIdx.x * 256 + threadIdx.x;
    if (idx < 1152 * 384) {
        int r = idx / 384, c = idx % 384;
        float v;
        if (r < 192)      v = Wq [(size_t)r * 384 + c];
        else if (r < 576) v = Wkv[(size_t)(r - 192) * 384 + c];
        else if (r < 720) v = Wqp[(size_t)(r - 576) * 384 + c];
        else              v = Wkvp[(size_t)(r - 720) * 384 + c];
        Wallb[idx] = bfr(v);
    }
    if (idx < 1152) {
        float v;
        if (idx < 192)      v = bq[idx];
        else if (idx < 576) v = bkv[idx - 192];
        else if (idx < 720) v = bqp[idx - 576];
        else                v = bkvp[idx - 720];
        ball[idx] = v;
    }
    if (idx < 2048 * 384) sb[idx] = bfr(s[idx]);
    if (idx < 384 * 576)  Woutb[idx] = bfr(Wout[idx]);
}

// ---------------------------------------------------------------------------
// bf16 MFMA GEMM (structure verified r7 at 128x128; tile now templated for
// grid saturation). C[m][n] = sum_k A[m][k]*W[n][k] + bias[n].
// 256 thr = 4 waves in 2x2; per wave WM x WN = (BM/2)x(BN/2).
// ---------------------------------------------------------------------------
template<int BM, int BN>
__global__ __launch_bounds__(256) void gemm_mfma(
    const ushort_t* __restrict__ A, const ushort_t* __restrict__ W,
    const float* __restrict__ bias, float* __restrict__ C,
    int M, int Nn, int K)
{
    constexpr int WM = BM / 2, WN = BN / 2;
    constexpr int MI = WM / 16, NJ = WN / 16;
    __shared__ ushort_t As[BM][40];
    __shared__ ushort_t Bs[BN][40];

    const int bm = blockIdx.y * BM;
    const int bn = blockIdx.x * BN;
    const int t  = threadIdx.x;
    const int w  = t >> 6, lane = t & 63;
    const int m  = lane & 15, quad = lane >> 4;
    const int wm = (w >> 1) * WM, wn = (w & 1) * WN;

    f4_t acc[MI][NJ];
    #pragma unroll
    for (int i2 = 0; i2 < MI; ++i2)
        #pragma unroll
        for (int j2 = 0; j2 < NJ; ++j2)
            acc[i2][j2] = (f4_t){0.f, 0.f, 0.f, 0.f};

    for (int k0 = 0; k0 < K; k0 += 32) {
        #pragma unroll
        for (int u = 0; u < BM / 64; ++u) {
            int e = t + u * 256;
            int r = e >> 2, kk = (e & 3) * 8;
            *(uint4*)&As[r][kk] = *(const uint4*)&A[(size_t)(bm + r) * K + k0 + kk];
        }
        #pragma unroll
        for (int u = 0; u < BN / 64; ++u) {
            int e = t + u * 256;
            int r = e >> 2, kk = (e & 3) * 8;
            *(uint4*)&Bs[r][kk] = *(const uint4*)&W[(size_t)(bn + r) * K + k0 + kk];
        }
        __syncthreads();
        bf8_t af[MI], bf[NJ];
        #pragma unroll
        for (int x = 0; x < MI; ++x) af[x] = *(const bf8_t*)&As[wm + x * 16 + m][quad * 8];
        #pragma unroll
        for (int x = 0; x < NJ; ++x) bf[x] = *(const bf8_t*)&Bs[wn + x * 16 + m][quad * 8];
        #pragma unroll
        for (int i2 = 0; i2 < MI; ++i2)
            #pragma unroll
            for (int j2 = 0; j2 < NJ; ++j2)
                acc[i2][j2] = __builtin_amdgcn_mfma_f32_16x16x32_bf16(
                    af[i2], bf[j2], acc[i2][j2], 0, 0, 0);
        __syncthreads();
    }

    #pragma unroll
    for (int j2 = 0; j2 < NJ; ++j2) {
        int col = bn + wn + j2 * 16 + m;
        float bb = bias[col];
        #pragma unroll
        for (int i2 = 0; i2 < MI; ++i2) {
            #pragma unroll
            for (int r = 0; r < 4; ++r) {
                int row = bm + wm + i2 * 16 + quad * 4 + r;
                C[(size_t)row * Nn + col] = acc[i2][j2][r] + bb;
            }
        }
    }
}

// ---------------------------------------------------------------------------
// pack_aug v2: LDS-staged for coalescing. Grid 256 blocks x 128 thr; block
// stages 8 Pall rows (coalesced float4), then 96 threads (nl 0..7, h 0..11)
// run the r7-verified per-(n,h) math from LDS.
// ---------------------------------------------------------------------------
__global__ __launch_bounds__(128) void pack_aug(
    const float* __restrict__ Pall, const float* __restrict__ rot,
    const float* __restrict__ trans, const float* __restrict__ mask,
    const float* __restrict__ hwv,
    ushort_t* __restrict__ AU, ushort_t* __restrict__ KU,
    ushort_t* __restrict__ VU)
{
    __shared__ float S[8][1156];   // 36992 B; stride 1156 breaks bank aliasing
    const int n0 = blockIdx.x * 8;
    const int t  = threadIdx.x;

    #pragma unroll
    for (int u = 0; u < 18; ++u) {
        int f = t + u * 128;             // 0..2303
        int rr = f / 288, c4 = f % 288;
        float4 v = *(const float4*)&Pall[(size_t)(n0 + rr) * PSTR + c4 * 4];
        *(float4*)&S[rr][c4 * 4] = v;
    }
    __syncthreads();

    if (t >= 96) return;
    const int nl = t & 7, h = t >> 3;    // h < 12
    const int n  = n0 + nl;
    const float* row = S[nl];

    const float whw = 0.5f * logf(1.0f + expf(hwv[h])) * 0.13608276348795434f;
    const float scale_a = 0.14433756729740643f;   // sqrt(1/48)

    float R[9], T[3];
    #pragma unroll
    for (int z = 0; z < 9; ++z) R[z] = rot[(size_t)n * 9 + z];
    #pragma unroll
    for (int d = 0; d < 3; ++d) T[d] = trans[(size_t)n * 3 + d];

    float qpv[12], q2 = 0.f;
    #pragma unroll
    for (int p = 0; p < 4; ++p) {
        float r0 = row[576 +   0 + h * 4 + p];
        float r1 = row[576 +  48 + h * 4 + p];
        float r2 = row[576 +  96 + h * 4 + p];
        #pragma unroll
        for (int d = 0; d < 3; ++d) {
            float o = R[d*3+0]*r0 + R[d*3+1]*r1 + R[d*3+2]*r2 + T[d];
            qpv[p * 3 + d] = o;
            q2 += o * o;
        }
    }

    float kpv[12], vpv[24], k2 = 0.f;
    #pragma unroll
    for (int pt = 0; pt < 12; ++pt) {
        float r0 = row[720 +   0 + h * 12 + pt];
        float r1 = row[720 + 144 + h * 12 + pt];
        float r2 = row[720 + 288 + h * 12 + pt];
        #pragma unroll
        for (int d = 0; d < 3; ++d) {
            float o = R[d*3+0]*r0 + R[d*3+1]*r1 + R[d*3+2]*r2 + T[d];
            if (pt < 4) { kpv[pt * 3 + d] = o; k2 += o * o; }
            else        { vpv[(pt - 4) * 3 + d] = o; }
        }
    }

    const float mi = mask[n];

    __align__(16) ushort_t a32[32];
    #pragma unroll
    for (int c = 0; c < 16; ++c) a32[c] = bfr(row[h * 16 + c] * scale_a);
    #pragma unroll
    for (int z = 0; z < 12; ++z) a32[16 + z] = bfr(qpv[z] * (2.0f * whw));
    a32[28] = bfr(-whw);
    a32[29] = bfr(-whw * q2);
    a32[30] = bfr(mi * MASKV);
    a32[31] = bfr(-MASKV);
    ushort_t* adst = AU + ((size_t)h * Nseq + n) * 32;
    #pragma unroll
    for (int u = 0; u < 4; ++u) ((uint4*)adst)[u] = ((const uint4*)a32)[u];

    const float* kvrow = row + 192 + h * 32;   // k[16] then v[16]
    __align__(16) ushort_t k32[32];
    #pragma unroll
    for (int c = 0; c < 16; ++c) k32[c] = bfr(kvrow[c]);
    #pragma unroll
    for (int z = 0; z < 12; ++z) k32[16 + z] = bfr(kpv[z]);
    k32[28] = bfr(k2);
    k32[29] = 0x3F80;
    k32[30] = bfr(mi);
    k32[31] = 0x3F80;
    ushort_t* kdst = KU + ((size_t)h * Nseq + n) * 32;
    #pragma unroll
    for (int u = 0; u < 4; ++u) ((uint4*)kdst)[u] = ((const uint4*)k32)[u];

    ushort_t* vb = VU + (size_t)h * 48 * Nseq + n;
    #pragma unroll
    for (int c = 0; c < 16; ++c) vb[(size_t)c * Nseq] = bfr(kvrow[16 + c]);
    #pragma unroll
    for (int z = 0; z < 24; ++z) vb[(size_t)(16 + z) * Nseq] = bfr(vpv[z]);
    vb[(size_t)40 * Nseq] = 0x3F80;
    #pragma unroll
    for (int c = 41; c < 48; ++c) vb[(size_t)c * Nseq] = 0;
}

__device__ __forceinline__ bf8_t expack(f4_t s) {   // exp -> bf16 low4, zero high
    s4_t p;
    p[0] = (short)bfr(__expf(s[0]));
    p[1] = (short)bfr(__expf(s[1]));
    p[2] = (short)bfr(__expf(s[2]));
    p[3] = (short)bfr(__expf(s[3]));
    s4_t z = (s4_t)0;
    return __builtin_shufflevector(p, z, 0, 1, 2, 3, 4, 5, 6, 7);
}

__device__ __forceinline__ bf8_t vpad(s4_t v) {     // V low4, zero high
    s4_t z = (s4_t)0;
    return __builtin_shufflevector(v, z, 0, 1, 2, 3, 4, 5, 6, 7);
}

// ---------------------------------------------------------------------------
// MFMA attention v3: NO LDS round-trip. Compute S^T = mfma(K, Q): its C/D
// (row=quad*4+r = j, col=m = i) is directly a PV A-frag with values at
// k=quad*8+u (u<4) and zero-high; V B-frags load rows j0+quad*4..+4 (8B) with
// zero-high (zero x zero = 0 contribution). Grid 768 = 12h x 64 iblocks(32).
// 4 waves split j (512 each); LDS sum-merge; fused fin epilogue.
// ---------------------------------------------------------------------------
__global__ __launch_bounds__(256, 3) void attn_mfma(
    const ushort_t* __restrict__ AU, const ushort_t* __restrict__ KU,
    const ushort_t* __restrict__ VU,
    const float* __restrict__ rot, const float* __restrict__ trans,
    ushort_t* __restrict__ featsb)
{
    __shared__ float red[4][32][49];   // 25088 B

    const int b    = blockIdx.x;
    const int h    = b >> 6;           // 0..11
    const int ib   = b & 63;           // 0..63
    const int t    = threadIdx.x;
    const int w    = t >> 6;
    const int lane = t & 63;
    const int m    = lane & 15;
    const int quad = lane >> 4;
    const int i0   = ib * 32;

    bf8_t afA = *(const bf8_t*)(AU + ((size_t)h * Nseq + i0 +      m) * 32 + quad * 8);
    bf8_t afB = *(const bf8_t*)(AU + ((size_t)h * Nseq + i0 + 16 + m) * 32 + quad * 8);

    f4_t acc[6];   // A0 A1 A2 B0 B1 B2  (V col blocks 0-15,16-31,32-47)
    #pragma unroll
    for (int z = 0; z < 6; ++z) acc[z] = (f4_t){0.f, 0.f, 0.f, 0.f};

    const int jb0 = w * 512;
    const ushort_t* kb_base = KU + ((size_t)h * Nseq + jb0 + m) * 32 + quad * 8;
    const ushort_t* v_base  = VU + ((size_t)h * 48 + m) * Nseq + jb0 + quad * 4;

    for (int jt = 0; jt < 16; ++jt) {
        const int j32 = jt * 32;
        bf8_t kb0 = *(const bf8_t*)(kb_base + (size_t)j32 * 32);
        bf8_t kb1 = *(const bf8_t*)(kb_base + (size_t)(j32 + 16) * 32);
        s4_t vX0 = *(const s4_t*)(v_base + j32);
        s4_t vX1 = *(const s4_t*)(v_base + 16 * Nseq + j32);
        s4_t vX2 = *(const s4_t*)(v_base + 32 * Nseq + j32);
        s4_t vY0 = *(const s4_t*)(v_base + j32 + 16);
        s4_t vY1 = *(const s4_t*)(v_base + 16 * Nseq + j32 + 16);
        s4_t vY2 = *(const s4_t*)(v_base + 32 * Nseq + j32 + 16);

        f4_t zz = (f4_t){0.f, 0.f, 0.f, 0.f};
        f4_t sXA = __builtin_amdgcn_mfma_f32_16x16x32_bf16(kb0, afA, zz, 0, 0, 0);
        f4_t sXB = __builtin_amdgcn_mfma_f32_16x16x32_bf16(kb0, afB, zz, 0, 0, 0);
        f4_t sYA = __builtin_amdgcn_mfma_f32_16x16x32_bf16(kb1, afA, zz, 0, 0, 0);
        f4_t sYB = __builtin_amdgcn_mfma_f32_16x16x32_bf16(kb1, afB, zz, 0, 0, 0);

        bf8_t pXA = expack(sXA), pXB = expack(sXB);
        bf8_t pYA = expack(sYA), pYB = expack(sYB);
        bf8_t f0 = vpad(vX0), f1 = vpad(vX1), f2 = vpad(vX2);
        bf8_t g0 = vpad(vY0), g1 = vpad(vY1), g2 = vpad(vY2);

        acc[0] = __builtin_amdgcn_mfma_f32_16x16x32_bf16(pXA, f0, acc[0], 0, 0, 0);
        acc[0] = __builtin_amdgcn_mfma_f32_16x16x32_bf16(pYA, g0, acc[0], 0, 0, 0);
        acc[1] = __builtin_amdgcn_mfma_f32_16x16x32_bf16(pXA, f1, acc[1], 0, 0, 0);
        acc[1] = __builtin_amdgcn_mfma_f32_16x16x32_bf16(pYA, g1, acc[1], 0, 0, 0);
        acc[2] = __builtin_amdgcn_mfma_f32_16x16x32_bf16(pXA, f2, acc[2], 0, 0, 0);
        acc[2] = __builtin_amdgcn_mfma_f32_16x16x32_bf16(pYA, g2, acc[2], 0, 0, 0);
        acc[3] = __builtin_amdgcn_mfma_f32_16x16x32_bf16(pXB, f0, acc[3], 0, 0, 0);
        acc[3] = __builtin_amdgcn_mfma_f32_16x16x32_bf16(pYB, g0, acc[3], 0, 0, 0);
        acc[4] = __builtin_amdgcn_mfma_f32_16x16x32_bf16(pXB, f1, acc[4], 0, 0, 0);
        acc[4] = __builtin_amdgcn_mfma_f32_16x16x32_bf16(pYB, g1, acc[4], 0, 0, 0);
        acc[5] = __builtin_amdgcn_mfma_f32_16x16x32_bf16(pXB, f2, acc[5], 0, 0, 0);
        acc[5] = __builtin_amdgcn_mfma_f32_16x16x32_bf16(pYB, g2, acc[5], 0, 0, 0);
    }

    // dump per-wave partials (C/D: row=quad*4+r -> i-local, col=m)
    #pragma unroll
    for (int r = 0; r < 4; ++r) {
        red[w][quad * 4 + r][m]           = acc[0][r];
        red[w][quad * 4 + r][16 + m]      = acc[1][r];
        red[w][quad * 4 + r][32 + m]      = acc[2][r];
        red[w][16 + quad * 4 + r][m]      = acc[3][r];
        red[w][16 + quad * 4 + r][16 + m] = acc[4][r];
        red[w][16 + quad * 4 + r][32 + m] = acc[5][r];
    }
    __syncthreads();

    // sum the 4 waves: 32*48 = 1536 entries, 6 per thread
    #pragma unroll
    for (int u = 0; u < 6; ++u) {
        int e = t + u * 256;
        int rr = e / 48, cc = e % 48;
        red[0][rr][cc] = red[0][rr][cc] + red[1][rr][cc] + red[2][rr][cc] + red[3][rr][cc];
    }
    __syncthreads();

    // fused epilogue (verified r3/r7 math): threads 0..31, one i-row each
    if (t < 32) {
        const int i = i0 + t;
        float L   = red[0][t][40];
        float inv = 1.0f / L;
        float o[40];
        #pragma unroll
        for (int z = 0; z < 40; ++z) o[z] = red[0][t][z] * inv;

        ushort_t* f = featsb + (size_t)i * 576;
        #pragma unroll
        for (int c = 0; c < 16; ++c) f[h * 16 + c] = bfr(o[c]);

        float R[9], T[3];
        #pragma unroll
        for (int z = 0; z < 9; ++z) R[z] = rot[(size_t)i * 9 + z];
        #pragma unroll
        for (int d = 0; d < 3; ++d) T[d] = trans[(size_t)i * 3 + d];

        #pragma unroll
        for (int p8 = 0; p8 < 8; ++p8) {
            float g0 = o[16 + p8 * 3 + 0] - T[0];
            float g1 = o[16 + p8 * 3 + 1] - T[1];
            float g2 = o[16 + p8 * 3 + 2] - T[2];
            float xx = R[0] * g0 + R[3] * g1 + R[6] * g2;
            float yy = R[1] * g0 + R[4] * g1 + R[7] * g2;
            float zz = R[2] * g0 + R[5] * g1 + R[8] * g2;
            float dist = sqrtf(xx * xx + yy * yy + zz * zz + EPSm);
            f[192 + h * 8 + p8] = bfr(xx);
            f[288 + h * 8 + p8] = bfr(yy);
            f[384 + h * 8 + p8] = bfr(zz);
            f[480 + h * 8 + p8] = bfr(dist);
        }
    }
}

// ---------------------------------------------------------------------------
extern "C" void kernel_launch(void* const* d_in, const int* in_sizes, int n_in,
                              void* d_out, int out_size, void* d_ws, size_t ws_size,
                              hipStream_t stream)
{
    const float* s     = (const float*)d_in[0];
    const float* rot   = (const float*)d_in[1];
    const float* trans = (const float*)d_in[2];
    const float* mask  = (const float*)d_in[3];
    const float* Wq    = (const float*)d_in[4];
    const float* bq    = (const float*)d_in[5];
    const float* Wkv   = (const float*)d_in[6];
    const float* bkv   = (const float*)d_in[7];
    const float* Wqp   = (const float*)d_in[8];
    const float* bqp   = (const float*)d_in[9];
    const float* Wkvp  = (const float*)d_in[10];
    const float* bkvp  = (const float*)d_in[11];
    const float* hwv   = (const float*)d_in[12];
    const float* Wout  = (const float*)d_in[13];
    const float* bout  = (const float*)d_in[14];
    float* out = (float*)d_out;
    float* ws  = (float*)d_ws;

    if (ws_size < (size_t)WS_FLOATS * sizeof(float)) return;

    float*    Pall   = ws + OFF_PALL;
    ushort_t* Wallb  = (ushort_t*)(ws + OFF_WALLB);
    float*    ball   = ws + OFF_BALL;
    ushort_t* sb     = (ushort_t*)(ws + OFF_SB);
    ushort_t* Woutb  = (ushort_t*)(ws + OFF_WOUTB);
    ushort_t* featsb = (ushort_t*)(ws + OFF_FEATSB);
    ushort_t* AU     = (ushort_t*)(ws + OFF_AU);
    ushort_t* KU     = (ushort_t*)(ws + OFF_KU);
    ushort_t* VU     = (ushort_t*)(ws + OFF_VU);

    prep<<<dim3(3072), 256, 0, stream>>>(s, Wout, Wq, Wkv, Wqp, Wkvp,
                                         bq, bkv, bqp, bkvp,
                                         Wallb, ball, sb, Woutb);

    gemm_mfma<128, 64><<<dim3(1152 / 64, 2048 / 128), 256, 0, stream>>>(
        sb, Wallb, ball, Pall, 2048, 1152, 384);

    pack_aug<<<dim3(256), 128, 0, stream>>>(Pall, rot, trans, mask, hwv,
                                            AU, KU, VU);

    attn_mfma<<<dim3(768), 256, 0, stream>>>(AU, KU, VU, rot, trans, featsb);

    gemm_mfma<64, 64><<<dim3(384 / 64, 2048 / 64), 256, 0, stream>>>(
        featsb, Woutb, bout, out, 2048, 384, 576);
}